// Round 19
// baseline (227.046 us; speedup 1.0000x reference)
//
#include <hip/hip_runtime.h>
#include <hip/hip_bf16.h>

// MoD transformer block: B=4, T=4096, D=1024, H=16, HD=64, CAP=512, DFF=2730
// Inputs fp32, output fp32. Round 19: GEMMs BK 64->32 (still dbuf 2-phase).
// r18 g2: MfmaUtil 19%, occ 13.9% (80KB LDS -> ~1 block/CU resident) —
// latency-bound from too few waves. BK=32 halves LDS: g1 24KB (6 blk/CU),
// g2 40KB (4 blk/CU); m97/m114 evidence: resident-wave overlap > barrier cost.

#define B_   4
#define T_   4096
#define D_   1024
#define H_   16
#define HD_  64
#define CAP_ 512
#define DFF_ 2730
#define DFFP 2752               // DFF padded to mult of 32 (K-path)
#define DFFR 2816               // DFF padded to mult of 128 (B-row tiles)
#define M_   (B_*CAP_)          // 2048 selected rows total

typedef __attribute__((ext_vector_type(8))) short          s16x8;
typedef __attribute__((ext_vector_type(8))) unsigned short u16x8;
typedef __attribute__((ext_vector_type(4))) float          f32x4;

__device__ __forceinline__ float bf2f(unsigned short u) {
    union { float f; unsigned int i; } v; v.i = ((unsigned int)u) << 16; return v.f;
}
__device__ __forceinline__ unsigned short f2bf(float f) {
    union { float f; unsigned int i; } v; v.f = f;
    unsigned int r = v.i + 0x7fffu + ((v.i >> 16) & 1u);   // RNE
    return (unsigned short)(r >> 16);
}

// async global->LDS, 16B per lane; LDS dest = wave-uniform base + lane*16
__device__ __forceinline__ void gload_lds16(const unsigned short* g, unsigned short* l) {
    __builtin_amdgcn_global_load_lds(
        (const __attribute__((address_space(1))) unsigned int*)g,
        (__attribute__((address_space(3))) unsigned int*)l, 16, 0, 0);
}

// ---------------- fused: out = x (fp32) + router scores ----------------
__global__ __launch_bounds__(256) void k_copy_router(const float* __restrict__ x,
                                                     const float* __restrict__ wr,
                                                     float* __restrict__ out,
                                                     float* __restrict__ sc) {
    int gw   = (blockIdx.x * 256 + threadIdx.x) >> 6;   // 0..B*T-1
    int lane = threadIdx.x & 63;
    const float* row = x + (size_t)gw * D_;
    float* orow = out + (size_t)gw * D_;
    float s = 0.f;
#pragma unroll
    for (int p = 0; p < 4; ++p) {
        int c = p * 256 + lane * 4;
        float4 xv = *(const float4*)(row + c);
        float4 wv = *(const float4*)(wr + c);
        *(float4*)(orow + c) = xv;
        s += xv.x * wv.x + xv.y * wv.y + xv.z * wv.z + xv.w * wv.w;
    }
#pragma unroll
    for (int o = 32; o; o >>= 1) s += __shfl_xor(s, o);
    if (lane == 0) sc[gw] = s;
}

// ---------------- fp32 -> bf16 flat convert ----------------
__global__ __launch_bounds__(256) void k_f2b(const float4* __restrict__ s,
                                             ushort4* __restrict__ d, int n4) {
    int i = blockIdx.x * 256 + threadIdx.x;
    int st = gridDim.x * 256;
    for (; i < n4; i += st) {
        float4 v = s[i];
        ushort4 o;
        o.x = f2bf(v.x); o.y = f2bf(v.y); o.z = f2bf(v.z); o.w = f2bf(v.w);
        d[i] = o;
    }
}

// ---------------- fp32 [rows][K] -> bf16 [rowsP][K], pad ROWS zeroed ----------------
__global__ __launch_bounds__(256) void k_f2b_rowpad(const float* __restrict__ src,
                                                    unsigned short* __restrict__ dst,
                                                    int kc, int rows, int total) {
    int g = blockIdx.x * 256 + threadIdx.x;
    int st = gridDim.x * 256;
    for (; g < total; g += st) {
        int row = g / kc;
        u16x8 v = {0, 0, 0, 0, 0, 0, 0, 0};
        if (row < rows) {
            const float* s = src + ((size_t)g) * 8;
#pragma unroll
            for (int j = 0; j < 2; ++j) {
                float4 f = *(const float4*)(s + 4 * j);
                v[4*j]   = f2bf(f.x); v[4*j+1] = f2bf(f.y);
                v[4*j+2] = f2bf(f.z); v[4*j+3] = f2bf(f.w);
            }
        }
        *(u16x8*)(dst + (size_t)g * 8) = v;
    }
}

// ---------------- fp32 [rows][K] -> bf16 [rows][Kp], pad COLS zeroed ----------------
__global__ __launch_bounds__(256) void k_f2b_pad(const float* __restrict__ src,
                                                 unsigned short* __restrict__ dst,
                                                 int K, int Kp, int rows) {
    int g = blockIdx.x * 256 + threadIdx.x;
    int ng = rows * (Kp >> 3);
    int st = gridDim.x * 256;
    for (; g < ng; g += st) {
        int row = g / (Kp >> 3);
        int c = (g - row * (Kp >> 3)) << 3;
        const float* s = src + (size_t)row * K + c;
        u16x8 v;
        if (c + 8 <= K) {
#pragma unroll
            for (int j = 0; j < 4; ++j) {
                float2 f = *(const float2*)(s + 2 * j);
                v[2*j] = f2bf(f.x); v[2*j+1] = f2bf(f.y);
            }
        } else {
#pragma unroll
            for (int j = 0; j < 8; ++j) v[j] = (c + j < K) ? f2bf(s[j]) : (unsigned short)0;
        }
        *(u16x8*)(dst + (size_t)row * Kp + c) = v;
    }
}

// ---------------- exact top-k via radix select + rank scatter ----------------
__global__ __launch_bounds__(1024) void k_topk(const float* __restrict__ sc,
                                               int* __restrict__ idx) {
    __shared__ unsigned int hist[256];
    __shared__ unsigned long long okeys[CAP_];
    __shared__ unsigned int ecand[T_];
    __shared__ unsigned int sprefix;
    __shared__ int skneed;
    __shared__ unsigned int scnt, ecnt;
    int t = threadIdx.x;
    const float* s = sc + (size_t)blockIdx.x * T_;

    unsigned int sb[4], ei[4];
#pragma unroll
    for (int j = 0; j < 4; ++j) {
        int i = j * 1024 + t;
        union { float f; unsigned int u; } v; v.f = s[i];
        unsigned int k = (v.u & 0x80000000u) ? ~v.u : (v.u | 0x80000000u);
        sb[j] = ~k;
        ei[j] = (unsigned int)i;
    }
    if (t == 0) { sprefix = 0; skneed = CAP_; scnt = 0; ecnt = 0; }

#pragma unroll
    for (int rs = 24; rs >= 0; rs -= 8) {
        if (t < 256) hist[t] = 0;
        __syncthreads();
        unsigned int pfx = sprefix;
#pragma unroll
        for (int j = 0; j < 4; ++j) {
            if (((unsigned long long)(sb[j] ^ pfx) >> (rs + 8)) == 0ULL)
                atomicAdd(&hist[(sb[j] >> rs) & 255u], 1u);
        }
        __syncthreads();
        if (t < 64) {
            unsigned int h0 = hist[t * 4], h1 = hist[t * 4 + 1];
            unsigned int h2 = hist[t * 4 + 2], h3 = hist[t * 4 + 3];
            unsigned int lsum = h0 + h1 + h2 + h3;
            unsigned int run = lsum;
#pragma unroll
            for (int d = 1; d < 64; d <<= 1) {
                unsigned int v = __shfl_up(run, d);
                if (t >= d) run += v;
            }
            unsigned int excl = run - lsum;
            int need = skneed;
            if (excl < (unsigned int)need && run >= (unsigned int)need) {
                unsigned int cum = excl;
                int b = t * 4;
                if (cum + h0 < (unsigned int)need) { cum += h0; ++b;
                    if (cum + h1 < (unsigned int)need) { cum += h1; ++b;
                        if (cum + h2 < (unsigned int)need) { cum += h2; ++b; } } }
                sprefix = pfx | ((unsigned int)b << rs);
                skneed = need - (int)cum;
            }
        }
        __syncthreads();
    }

    unsigned int Sstar = sprefix;
    int neq = skneed;
#pragma unroll
    for (int j = 0; j < 4; ++j) {
        if (sb[j] < Sstar) {
            unsigned int p = atomicAdd(&scnt, 1u);
            okeys[p] = ((unsigned long long)sb[j] << 32) | ei[j];
        } else if (sb[j] == Sstar) {
            unsigned int p = atomicAdd(&ecnt, 1u);
            ecand[p] = ei[j];
        }
    }
    __syncthreads();
    if (t == 0) {
        unsigned int base = scnt;
        unsigned int ne = ecnt;
        for (int q = 0; q < neq; ++q) {
            unsigned int mn = 0xffffffffu; int mi = 0;
            for (unsigned int e = 0; e < ne; ++e)
                if (ecand[e] < mn) { mn = ecand[e]; mi = (int)e; }
            okeys[base + q] = ((unsigned long long)Sstar << 32) | mn;
            ecand[mi] = 0xffffffffu;
        }
    }
    __syncthreads();
    if (t < CAP_) {
        unsigned long long mine = okeys[t];
        int r = 0;
#pragma unroll 8
        for (int q = 0; q < CAP_; ++q) r += (okeys[q] < mine) ? 1 : 0;
        idx[blockIdx.x * CAP_ + r] = (int)(mine & 0xffffffffu);
    }
}

// ---------------- gather + RMSNorm(g1) -> h (bf16) ----------------
__global__ __launch_bounds__(256) void k_gather_rms(const float* __restrict__ x,
                                                    const int* __restrict__ idx,
                                                    const float* __restrict__ g,
                                                    unsigned short* __restrict__ h) {
    int r = blockIdx.x;
    int b = r >> 9;
    int src = idx[r] & (T_ - 1);
    const float* xr = x + ((size_t)b * T_ + src) * D_;
    int c = threadIdx.x * 4;
    float4 xv = *(const float4*)(xr + c);
    float ss = xv.x*xv.x + xv.y*xv.y + xv.z*xv.z + xv.w*xv.w;
#pragma unroll
    for (int o = 32; o; o >>= 1) ss += __shfl_xor(ss, o);
    __shared__ float red[4];
    int lane = threadIdx.x & 63, w = threadIdx.x >> 6;
    if (lane == 0) red[w] = ss;
    __syncthreads();
    float tot = red[0] + red[1] + red[2] + red[3];
    float scale = rsqrtf(tot * (1.f / D_) + 1e-6f);
    float4 gv = *(const float4*)(g + c);
    ushort4 hv;
    hv.x = f2bf(xv.x * scale * gv.x);
    hv.y = f2bf(xv.y * scale * gv.y);
    hv.z = f2bf(xv.z * scale * gv.z);
    hv.w = f2bf(xv.w * scale * gv.w);
    *(ushort4*)(h + (size_t)r * D_ + c) = hv;
}

// ---------------- MFMA GEMM 64x128, BK=32, dbuf 2-phase, gload_lds+XOR ----------------
// LDS 24KB -> ~6 blocks/CU. Swizzle: 4 col-blocks of 16B, phys = logical^(row&3),
// applied on the global source (staging) and the ds_read address (rule #21).
__global__ __launch_bounds__(256) void k_gemm64g(const unsigned short* __restrict__ A,
                                                 const unsigned short* __restrict__ Bw,
                                                 unsigned short* __restrict__ C,
                                                 int Nout, int Kr) {
    __shared__ __align__(16) unsigned short As[2][64 * 32];    // 8KB
    __shared__ __align__(16) unsigned short Bs[2][128 * 32];   // 16KB
    int m0 = blockIdx.x * 64;
    int n0 = blockIdx.y * 128;
    int t = threadIdx.x;
    int w = t >> 6, lane = t & 63;
    int lr = lane & 15, lg = lane >> 4;
    int l4 = lane >> 2, lm4 = lane & 3;    // staging: 16 rows/wave-inst, 4 colblks

    int arow = w * 16 + l4;                               // A rows for this wave
    int acb  = lm4 ^ (arow & 3);
    int brow0 = w * 32 + l4, brow1 = w * 32 + 16 + l4;    // B rows (2 insts)
    int bcb0 = lm4 ^ (brow0 & 3), bcb1 = lm4 ^ (brow1 & 3);

    f32x4 acc[4][2];
#pragma unroll
    for (int mi = 0; mi < 4; ++mi)
#pragma unroll
        for (int ni = 0; ni < 2; ++ni) acc[mi][ni] = {0.f, 0.f, 0.f, 0.f};

#define STAGE_G(buf, k0)                                                           \
    {                                                                              \
        gload_lds16(A + (size_t)(m0 + arow) * Kr + (k0) + acb * 8,                 \
                    &As[buf][(w * 16) * 32]);                                      \
        gload_lds16(Bw + (size_t)(n0 + brow0) * Kr + (k0) + bcb0 * 8,              \
                    &Bs[buf][(w * 32) * 32]);                                      \
        gload_lds16(Bw + (size_t)(n0 + brow1) * Kr + (k0) + bcb1 * 8,              \
                    &Bs[buf][(w * 32 + 16) * 32]);                                 \
    }

    int nk = Kr >> 5;
    STAGE_G(0, 0);
    __syncthreads();
    for (int kt = 0; kt < nk; ++kt) {
        int cur = kt & 1;
        if (kt + 1 < nk) STAGE_G(cur ^ 1, (kt + 1) << 5);
        s16x8 af[4], bf[2];
#pragma unroll
        for (int i = 0; i < 4; ++i) {
            int row = i * 16 + lr;
            int pb = lg ^ (row & 3);
            af[i] = *(const s16x8*)&As[cur][row * 32 + pb * 8];
        }
#pragma unroll
        for (int i = 0; i < 2; ++i) {
            int row = w * 32 + i * 16 + lr;
            int pb = lg ^ (row & 3);
            bf[i] = *(const s16x8*)&Bs[cur][row * 32 + pb * 8];
        }
#pragma unroll
        for (int mi = 0; mi < 4; ++mi)
#pragma unroll
            for (int ni = 0; ni < 2; ++ni)
                acc[mi][ni] = __builtin_amdgcn_mfma_f32_16x16x32_bf16(af[mi], bf[ni],
                                                                      acc[mi][ni], 0, 0, 0);
        __syncthreads();
    }
#undef STAGE_G
    int orow0 = m0 + (lg << 2);
    int ocol0 = n0 + w * 32 + lr;
#pragma unroll
    for (int ni = 0; ni < 2; ++ni) {
        int col = ocol0 + ni * 16;
        if (col < Nout) {
#pragma unroll
            for (int mi = 0; mi < 4; ++mi)
#pragma unroll
                for (int i = 0; i < 4; ++i)
                    C[(size_t)(orow0 + mi * 16 + i) * Nout + col] = f2bf(acc[mi][ni][i]);
        }
    }
}

// ---------------- FUSED W1/W2 GEMM, BK=32 dbuf: F = silu(A*B1^T)*(A*B2^T) ----------------
// LDS 40KB -> 4 blocks/CU.
__global__ __launch_bounds__(256) void k_gemm64g2(const unsigned short* __restrict__ A,
                                                  const unsigned short* __restrict__ B1,
                                                  const unsigned short* __restrict__ B2,
                                                  unsigned short* __restrict__ F,
                                                  int Nout, int Kr) {
    __shared__ __align__(16) unsigned short As[2][64 * 32];     // 8KB
    __shared__ __align__(16) unsigned short B1s[2][128 * 32];   // 16KB
    __shared__ __align__(16) unsigned short B2s[2][128 * 32];   // 16KB
    int m0 = blockIdx.x * 64;
    int n0 = blockIdx.y * 128;
    int t = threadIdx.x;
    int w = t >> 6, lane = t & 63;
    int lr = lane & 15, lg = lane >> 4;
    int l4 = lane >> 2, lm4 = lane & 3;

    int arow = w * 16 + l4;
    int acb  = lm4 ^ (arow & 3);
    int brow0 = w * 32 + l4, brow1 = w * 32 + 16 + l4;
    int bcb0 = lm4 ^ (brow0 & 3), bcb1 = lm4 ^ (brow1 & 3);

    f32x4 accU[4][2], accG[4][2];
#pragma unroll
    for (int mi = 0; mi < 4; ++mi)
#pragma unroll
        for (int ni = 0; ni < 2; ++ni) {
            accU[mi][ni] = {0.f, 0.f, 0.f, 0.f};
            accG[mi][ni] = {0.f, 0.f, 0.f, 0.f};
        }

#define STAGE_G2(buf, k0)                                                          \
    {                                                                              \
        gload_lds16(A + (size_t)(m0 + arow) * Kr + (k0) + acb * 8,                 \
                    &As[buf][(w * 16) * 32]);                                      \
        size_t go0 = (size_t)(n0 + brow0) * Kr + (k0) + bcb0 * 8;                  \
        size_t go1 = (size_t)(n0 + brow1) * Kr + (k0) + bcb1 * 8;                  \
        gload_lds16(B1 + go0, &B1s[buf][(w * 32) * 32]);                           \
        gload_lds16(B1 + go1, &B1s[buf][(w * 32 + 16) * 32]);                      \
        gload_lds16(B2 + go0, &B2s[buf][(w * 32) * 32]);                           \
        gload_lds16(B2 + go1, &B2s[buf][(w * 32 + 16) * 32]);                      \
    }

    int nk = Kr >> 5;
    STAGE_G2(0, 0);
    __syncthreads();
    for (int kt = 0; kt < nk; ++kt) {
        int cur = kt & 1;
        if (kt + 1 < nk) STAGE_G2(cur ^ 1, (kt + 1) << 5);
        s16x8 af[4], b1f[2], b2f[2];
#pragma unroll
        for (int i = 0; i < 4; ++i) {
            int row = i * 16 + lr;
            int pb = lg ^ (row & 3);
            af[i] = *(const s16x8*)&As[cur][row * 32 + pb * 8];
        }
#pragma unroll
        for (int i = 0; i < 2; ++i) {
            int row = w * 32 + i * 16 + lr;
            int pb = lg ^ (row & 3);
            b1f[i] = *(const s16x8*)&B1s[cur][row * 32 + pb * 8];
            b2f[i] = *(const s16x8*)&B2s[cur][row * 32 + pb * 8];
        }
#pragma unroll
        for (int mi = 0; mi < 4; ++mi)
#pragma unroll
            for (int ni = 0; ni < 2; ++ni) {
                accU[mi][ni] = __builtin_amdgcn_mfma_f32_16x16x32_bf16(af[mi], b1f[ni],
                                                                       accU[mi][ni], 0, 0, 0);
                accG[mi][ni] = __builtin_amdgcn_mfma_f32_16x16x32_bf16(af[mi], b2f[ni],
                                                                       accG[mi][ni], 0, 0, 0);
            }
        __syncthreads();
    }
#undef STAGE_G2
    int orow0 = m0 + (lg << 2);
    int ocol0 = n0 + w * 32 + lr;
#pragma unroll
    for (int ni = 0; ni < 2; ++ni) {
        int col = ocol0 + ni * 16;
        if (col < Nout) {
#pragma unroll
            for (int mi = 0; mi < 4; ++mi)
#pragma unroll
                for (int i = 0; i < 4; ++i) {
                    float u = accU[mi][ni][i];
                    float sl = u / (1.f + __expf(-u));
                    F[(size_t)(orow0 + mi * 16 + i) * Nout + col] = f2bf(sl * accG[mi][ni][i]);
                }
        }
    }
}

// ---------------- MFMA flash attention (causal, gathered order) ----------------
__global__ __launch_bounds__(256) void k_attn_mfma(const unsigned short* __restrict__ qkv,
                                                   unsigned short* __restrict__ o) {
    __shared__ __align__(16) unsigned short Ks[32][72];
    __shared__ __align__(16) unsigned short Vt[64][40];
    __shared__ __align__(16) unsigned short Ps[4][16][40];
    int qt = blockIdx.x, h = blockIdx.y, b = blockIdx.z;
    int q0 = qt * 64;
    int t = threadIdx.x, w = t >> 6, lane = t & 63;
    int lr = lane & 15, lg = lane >> 4;
    const unsigned short* base = qkv + (size_t)b * CAP_ * 3 * D_;

    int qrow = q0 + w * 16 + lr;
    const unsigned short* qp = base + (size_t)qrow * 3 * D_ + h * 64;
    s16x8 aq0 = *(const s16x8*)(qp + lg * 8);
    s16x8 aq1 = *(const s16x8*)(qp + 32 + lg * 8);

    f32x4 zero = {0.f, 0.f, 0.f, 0.f};
    f32x4 oacc[4] = {zero, zero, zero, zero};
    float m_[4], l_[4];
#pragma unroll
    for (int i = 0; i < 4; ++i) { m_[i] = -3.0e38f; l_[i] = 0.f; }

    int qbase = q0 + w * 16 + lg * 4;
    int ntile = (q0 + 64) >> 5;

    int skv = t >> 3, sc = (t & 7) * 8;
    for (int kt = 0; kt < ntile; ++kt) {
        int kv0 = kt << 5;
        {
            const unsigned short* kr = base + (size_t)(kv0 + skv) * 3 * D_ + D_     + h * 64 + sc;
            const unsigned short* vr = base + (size_t)(kv0 + skv) * 3 * D_ + 2 * D_ + h * 64 + sc;
            *(u16x8*)&Ks[skv][sc] = *(const u16x8*)kr;
            u16x8 vv = *(const u16x8*)vr;
#pragma unroll
            for (int j = 0; j < 8; ++j) Vt[sc + j][skv] = vv[j];
        }
        __syncthreads();
        f32x4 s0 = zero, s1 = zero;
        s16x8 k00 = *(const s16x8*)&Ks[lr][lg * 8];
        s16x8 k01 = *(const s16x8*)&Ks[lr][32 + lg * 8];
        s16x8 k10 = *(const s16x8*)&Ks[16 + lr][lg * 8];
        s16x8 k11 = *(const s16x8*)&Ks[16 + lr][32 + lg * 8];
        s0 = __builtin_amdgcn_mfma_f32_16x16x32_bf16(aq0, k00, s0, 0, 0, 0);
        s0 = __builtin_amdgcn_mfma_f32_16x16x32_bf16(aq1, k01, s0, 0, 0, 0);
        s1 = __builtin_amdgcn_mfma_f32_16x16x32_bf16(aq0, k10, s1, 0, 0, 0);
        s1 = __builtin_amdgcn_mfma_f32_16x16x32_bf16(aq1, k11, s1, 0, 0, 0);
#pragma unroll
        for (int i = 0; i < 4; ++i) {
            float v0 = s0[i] * 0.125f, v1 = s1[i] * 0.125f;
            if (kv0 + lr      > qbase + i) v0 = -3.0e38f;
            if (kv0 + 16 + lr > qbase + i) v1 = -3.0e38f;
            s0[i] = v0; s1[i] = v1;
        }
        float pm[4];
#pragma unroll
        for (int i = 0; i < 4; ++i) pm[i] = fmaxf(s0[i], s1[i]);
#pragma unroll
        for (int d = 1; d < 16; d <<= 1) {
#pragma unroll
            for (int i = 0; i < 4; ++i) pm[i] = fmaxf(pm[i], __shfl_xor(pm[i], d));
        }
        float p0[4], p1[4], ps[4], scl[4];
#pragma unroll
        for (int i = 0; i < 4; ++i) {
            float mn = fmaxf(m_[i], pm[i]);
            scl[i] = __expf(m_[i] - mn);
            p0[i] = __expf(s0[i] - mn);
            p1[i] = __expf(s1[i] - mn);
            ps[i] = p0[i] + p1[i];
            m_[i] = mn;
        }
#pragma unroll
        for (int d = 1; d < 16; d <<= 1) {
#pragma unroll
            for (int i = 0; i < 4; ++i) ps[i] += __shfl_xor(ps[i], d);
        }
#pragma unroll
        for (int i = 0; i < 4; ++i) l_[i] = l_[i] * scl[i] + ps[i];
#pragma unroll
        for (int dg = 0; dg < 4; ++dg)
#pragma unroll
            for (int i = 0; i < 4; ++i) oacc[dg][i] *= scl[i];
#pragma unroll
        for (int i = 0; i < 4; ++i) {
            Ps[w][lg * 4 + i][lr]      = f2bf(p0[i]);
            Ps[w][lg * 4 + i][16 + lr] = f2bf(p1[i]);
        }
        __syncthreads();
        s16x8 pa = *(const s16x8*)&Ps[w][lr][lg * 8];
#pragma unroll
        for (int dg = 0; dg < 4; ++dg) {
            s16x8 vf = *(const s16x8*)&Vt[dg * 16 + lr][lg * 8];
            oacc[dg] = __builtin_amdgcn_mfma_f32_16x16x32_bf16(pa, vf, oacc[dg], 0, 0, 0);
        }
        __syncthreads();
    }
    unsigned short* orow = o + ((size_t)(b * CAP_ + qbase)) * D_ + h * 64;
#pragma unroll
    for (int i = 0; i < 4; ++i) {
        float inv = 1.f / l_[i];
#pragma unroll
        for (int dg = 0; dg < 4; ++dg)
            orow[(size_t)i * D_ + dg * 16 + lr] = f2bf(oacc[dg][i] * inv);
    }
}

// ---------------- y = x_sel + xattn; h2 = rmsnorm(y, g2) ----------------
__global__ __launch_bounds__(256) void k_add_rms(const float* __restrict__ x,
                                                 const int* __restrict__ idx,
                                                 const unsigned short* __restrict__ xattn,
                                                 const float* __restrict__ g,
                                                 unsigned short* __restrict__ y,
                                                 unsigned short* __restrict__ h) {
    int r = blockIdx.x;
    int b = r >> 9;
    int src = idx[r] & (T_ - 1);
    int c = threadIdx.x * 4;
    const float* xr = x + ((size_t)b * T_ + src) * D_;
    float4 xv = *(const float4*)(xr + c);
    size_t off = (size_t)r * D_ + c;
    ushort4 a4 = *(const ushort4*)(xattn + off);
    float v0 = xv.x + bf2f(a4.x);
    float v1 = xv.y + bf2f(a4.y);
    float v2 = xv.z + bf2f(a4.z);
    float v3 = xv.w + bf2f(a4.w);
    float ss = v0*v0 + v1*v1 + v2*v2 + v3*v3;
#pragma unroll
    for (int o = 32; o; o >>= 1) ss += __shfl_xor(ss, o);
    __shared__ float red[4];
    int lane = threadIdx.x & 63, w = threadIdx.x >> 6;
    if (lane == 0) red[w] = ss;
    __syncthreads();
    float tot = red[0] + red[1] + red[2] + red[3];
    float scale = rsqrtf(tot * (1.f / D_) + 1e-6f);
    ushort4 yv;
    yv.x = f2bf(v0); yv.y = f2bf(v1); yv.z = f2bf(v2); yv.w = f2bf(v3);
    *(ushort4*)(y + off) = yv;
    float4 gv = *(const float4*)(g + c);
    ushort4 hv;
    hv.x = f2bf(v0 * scale * gv.x);
    hv.y = f2bf(v1 * scale * gv.y);
    hv.z = f2bf(v2 * scale * gv.z);
    hv.w = f2bf(v3 * scale * gv.w);
    *(ushort4*)(h + off) = hv;
}

// ---------------- scatter: out[b, idx, :] = y + xff  (fp32 out) ----------------
__global__ __launch_bounds__(256) void k_scatter(const unsigned short* __restrict__ y,
                                                 const unsigned short* __restrict__ xff,
                                                 const int* __restrict__ idx,
                                                 float* __restrict__ out) {
    int r = blockIdx.x;
    int b = r >> 9;
    int dst = idx[r] & (T_ - 1);
    int c = threadIdx.x * 4;
    size_t src = (size_t)r * D_ + c;
    ushort4 a4 = *(const ushort4*)(y + src);
    ushort4 f4 = *(const ushort4*)(xff + src);
    float4 o4;
    o4.x = bf2f(a4.x) + bf2f(f4.x);
    o4.y = bf2f(a4.y) + bf2f(f4.y);
    o4.z = bf2f(a4.z) + bf2f(f4.z);
    o4.w = bf2f(a4.w) + bf2f(f4.w);
    *(float4*)(out + ((size_t)b * T_ + dst) * D_ + c) = o4;
}

extern "C" void kernel_launch(void* const* d_in, const int* in_sizes, int n_in,
                              void* d_out, int out_size, void* d_ws, size_t ws_size,
                              hipStream_t stream) {
    const float* x     = (const float*)d_in[0];
    const float* w_rt  = (const float*)d_in[1];
    const float* W_qkv = (const float*)d_in[2];
    const float* W_out = (const float*)d_in[3];
    const float* g1    = (const float*)d_in[4];
    const float* g2    = (const float*)d_in[5];
    const float* W1    = (const float*)d_in[6];
    const float* W2    = (const float*)d_in[7];
    const float* W3    = (const float*)d_in[8];
    float* out = (float*)d_out;

    // ---- workspace: ~37 MiB (identical to r15-r18) ----
    char* p = (char*)d_ws;
    float* scores = (float*)p;
    int*   idx    = (int*)(p + 65536);
    size_t off = 131072;
    const size_t WPAD = (size_t)DFFR * D_;
    unsigned short* WBIG = (unsigned short*)(p + off); off += 2 * WPAD * 2;
    unsigned short* WB2  = WBIG + WPAD;
    unsigned short* R1   = (unsigned short*)(p + off); off += (size_t)M_*3*D_*2;
    unsigned short* R2   = (unsigned short*)(p + off); off += (size_t)M_*D_*2;
    unsigned short* R3   = (unsigned short*)(p + off); off += (size_t)M_*D_*2;
    unsigned short* R4   = (unsigned short*)(p + off); off += (size_t)M_*D_*2;

    unsigned short* h1    = R2;
    unsigned short* qkvb  = R1;
    unsigned short* attno = R2;   // after h1 dead
    unsigned short* xattn = R3;
    unsigned short* ybuf  = R4;
    unsigned short* h2b   = R2;   // after attno dead
    unsigned short* fbuf  = R1;   // after qkvb dead; [2048][DFFP]
    unsigned short* xffb  = R3;   // after xattn dead

    // 1+2. out = x (pass-through) + router scores, one x read
    k_copy_router<<<(B_*T_) / 4, 256, 0, stream>>>(x, w_rt, out, scores);
    // 3. exact top-k
    k_topk<<<B_, 1024, 0, stream>>>(scores, idx);
    // 4. gather + rmsnorm(g1) -> h1 (bf16)
    k_gather_rms<<<M_, 256, 0, stream>>>(x, idx, g1, h1);
    // 5. qkv = h1 @ W_qkv^T   [2048 x 3072], K=1024
    k_f2b<<<2048, 256, 0, stream>>>((const float4*)W_qkv, (ushort4*)WBIG, (3*D_*D_) / 4);
    k_gemm64g<<<dim3(M_/64, 3*D_/128), 256, 0, stream>>>(h1, WBIG, qkvb, 3*D_, D_);
    // 6. MFMA flash attention
    k_attn_mfma<<<dim3(CAP_/64, H_, B_), 256, 0, stream>>>(qkvb, attno);
    // 7. x_attn = o @ W_out^T  [2048 x 1024], K=1024
    k_f2b<<<1024, 256, 0, stream>>>((const float4*)W_out, (ushort4*)WBIG, (D_*D_) / 4);
    k_gemm64g<<<dim3(M_/64, D_/128), 256, 0, stream>>>(attno, WBIG, xattn, D_, D_);
    // 8. y = x_sel + xattn; h2 = rmsnorm(y, g2)
    k_add_rms<<<M_, 256, 0, stream>>>(x, idx, xattn, g2, ybuf, h2b);
    // 9+10. f = silu(h2@W1^T) * (h2@W2^T)  — FUSED
    k_f2b_rowpad<<<2048, 256, 0, stream>>>(W1, WBIG, D_/8, DFF_, DFFR*(D_/8));
    k_f2b_rowpad<<<2048, 256, 0, stream>>>(W2, WB2,  D_/8, DFF_, DFFR*(D_/8));
    k_gemm64g2<<<dim3(M_/64, DFFR/128), 256, 0, stream>>>(h2b, WBIG, WB2, fbuf,
                                                          DFFP, D_);
    // 11. x_ff = f @ W3^T   [2048 x 1024], K=DFFP
    k_f2b_pad<<<2048, 256, 0, stream>>>(W3, WBIG, DFF_, DFFP, D_);
    k_gemm64g<<<dim3(M_/64, D_/128), 256, 0, stream>>>(fbuf, WBIG, xffb, D_, DFFP);
    // 12. out[b, idx, :] = y + x_ff  (fp32)
    k_scatter<<<M_, 256, 0, stream>>>(ybuf, xffb, idx, out);
}

// Round 20
// 207.482 us; speedup vs baseline: 1.0943x; 1.0943x over previous
//
#include <hip/hip_runtime.h>
#include <hip/hip_bf16.h>

// MoD transformer block: B=4, T=4096, D=1024, H=16, HD=64, CAP=512, DFF=2730
// Inputs fp32, output fp32. Round 20:
//  (a) GEMMs reverted to r18 (BK=64 dbuf, ^(row&7) swizzle, 0 conflicts).
//      r19's BK=32 regressed: ^(row&3) swizzle left 8-way conflicts (2.1e6)
//      and doubled barriers; occupancy never rose.
//  (b) Attention KV-tile 32 -> 64: half the barriers, 2x MFMA per phase.

#define B_   4
#define T_   4096
#define D_   1024
#define H_   16
#define HD_  64
#define CAP_ 512
#define DFF_ 2730
#define DFFP 2752               // DFF padded to mult of 64 (K-path)
#define DFFR 2816               // DFF padded to mult of 128 (B-row tiles)
#define M_   (B_*CAP_)          // 2048 selected rows total

typedef __attribute__((ext_vector_type(8))) short          s16x8;
typedef __attribute__((ext_vector_type(8))) unsigned short u16x8;
typedef __attribute__((ext_vector_type(4))) float          f32x4;

__device__ __forceinline__ float bf2f(unsigned short u) {
    union { float f; unsigned int i; } v; v.i = ((unsigned int)u) << 16; return v.f;
}
__device__ __forceinline__ unsigned short f2bf(float f) {
    union { float f; unsigned int i; } v; v.f = f;
    unsigned int r = v.i + 0x7fffu + ((v.i >> 16) & 1u);   // RNE
    return (unsigned short)(r >> 16);
}

// async global->LDS, 16B per lane; LDS dest = wave-uniform base + lane*16
__device__ __forceinline__ void gload_lds16(const unsigned short* g, unsigned short* l) {
    __builtin_amdgcn_global_load_lds(
        (const __attribute__((address_space(1))) unsigned int*)g,
        (__attribute__((address_space(3))) unsigned int*)l, 16, 0, 0);
}

// ---------------- fused: out = x (fp32) + router scores ----------------
__global__ __launch_bounds__(256) void k_copy_router(const float* __restrict__ x,
                                                     const float* __restrict__ wr,
                                                     float* __restrict__ out,
                                                     float* __restrict__ sc) {
    int gw   = (blockIdx.x * 256 + threadIdx.x) >> 6;   // 0..B*T-1
    int lane = threadIdx.x & 63;
    const float* row = x + (size_t)gw * D_;
    float* orow = out + (size_t)gw * D_;
    float s = 0.f;
#pragma unroll
    for (int p = 0; p < 4; ++p) {
        int c = p * 256 + lane * 4;
        float4 xv = *(const float4*)(row + c);
        float4 wv = *(const float4*)(wr + c);
        *(float4*)(orow + c) = xv;
        s += xv.x * wv.x + xv.y * wv.y + xv.z * wv.z + xv.w * wv.w;
    }
#pragma unroll
    for (int o = 32; o; o >>= 1) s += __shfl_xor(s, o);
    if (lane == 0) sc[gw] = s;
}

// ---------------- fp32 -> bf16 flat convert ----------------
__global__ __launch_bounds__(256) void k_f2b(const float4* __restrict__ s,
                                             ushort4* __restrict__ d, int n4) {
    int i = blockIdx.x * 256 + threadIdx.x;
    int st = gridDim.x * 256;
    for (; i < n4; i += st) {
        float4 v = s[i];
        ushort4 o;
        o.x = f2bf(v.x); o.y = f2bf(v.y); o.z = f2bf(v.z); o.w = f2bf(v.w);
        d[i] = o;
    }
}

// ---------------- fp32 [rows][K] -> bf16 [rowsP][K], pad ROWS zeroed ----------------
__global__ __launch_bounds__(256) void k_f2b_rowpad(const float* __restrict__ src,
                                                    unsigned short* __restrict__ dst,
                                                    int kc, int rows, int total) {
    int g = blockIdx.x * 256 + threadIdx.x;
    int st = gridDim.x * 256;
    for (; g < total; g += st) {
        int row = g / kc;
        u16x8 v = {0, 0, 0, 0, 0, 0, 0, 0};
        if (row < rows) {
            const float* s = src + ((size_t)g) * 8;
#pragma unroll
            for (int j = 0; j < 2; ++j) {
                float4 f = *(const float4*)(s + 4 * j);
                v[4*j]   = f2bf(f.x); v[4*j+1] = f2bf(f.y);
                v[4*j+2] = f2bf(f.z); v[4*j+3] = f2bf(f.w);
            }
        }
        *(u16x8*)(dst + (size_t)g * 8) = v;
    }
}

// ---------------- fp32 [rows][K] -> bf16 [rows][Kp], pad COLS zeroed ----------------
__global__ __launch_bounds__(256) void k_f2b_pad(const float* __restrict__ src,
                                                 unsigned short* __restrict__ dst,
                                                 int K, int Kp, int rows) {
    int g = blockIdx.x * 256 + threadIdx.x;
    int ng = rows * (Kp >> 3);
    int st = gridDim.x * 256;
    for (; g < ng; g += st) {
        int row = g / (Kp >> 3);
        int c = (g - row * (Kp >> 3)) << 3;
        const float* s = src + (size_t)row * K + c;
        u16x8 v;
        if (c + 8 <= K) {
#pragma unroll
            for (int j = 0; j < 4; ++j) {
                float2 f = *(const float2*)(s + 2 * j);
                v[2*j] = f2bf(f.x); v[2*j+1] = f2bf(f.y);
            }
        } else {
#pragma unroll
            for (int j = 0; j < 8; ++j) v[j] = (c + j < K) ? f2bf(s[j]) : (unsigned short)0;
        }
        *(u16x8*)(dst + (size_t)row * Kp + c) = v;
    }
}

// ---------------- exact top-k via radix select + rank scatter ----------------
__global__ __launch_bounds__(1024) void k_topk(const float* __restrict__ sc,
                                               int* __restrict__ idx) {
    __shared__ unsigned int hist[256];
    __shared__ unsigned long long okeys[CAP_];
    __shared__ unsigned int ecand[T_];
    __shared__ unsigned int sprefix;
    __shared__ int skneed;
    __shared__ unsigned int scnt, ecnt;
    int t = threadIdx.x;
    const float* s = sc + (size_t)blockIdx.x * T_;

    unsigned int sb[4], ei[4];
#pragma unroll
    for (int j = 0; j < 4; ++j) {
        int i = j * 1024 + t;
        union { float f; unsigned int u; } v; v.f = s[i];
        unsigned int k = (v.u & 0x80000000u) ? ~v.u : (v.u | 0x80000000u);
        sb[j] = ~k;
        ei[j] = (unsigned int)i;
    }
    if (t == 0) { sprefix = 0; skneed = CAP_; scnt = 0; ecnt = 0; }

#pragma unroll
    for (int rs = 24; rs >= 0; rs -= 8) {
        if (t < 256) hist[t] = 0;
        __syncthreads();
        unsigned int pfx = sprefix;
#pragma unroll
        for (int j = 0; j < 4; ++j) {
            if (((unsigned long long)(sb[j] ^ pfx) >> (rs + 8)) == 0ULL)
                atomicAdd(&hist[(sb[j] >> rs) & 255u], 1u);
        }
        __syncthreads();
        if (t < 64) {
            unsigned int h0 = hist[t * 4], h1 = hist[t * 4 + 1];
            unsigned int h2 = hist[t * 4 + 2], h3 = hist[t * 4 + 3];
            unsigned int lsum = h0 + h1 + h2 + h3;
            unsigned int run = lsum;
#pragma unroll
            for (int d = 1; d < 64; d <<= 1) {
                unsigned int v = __shfl_up(run, d);
                if (t >= d) run += v;
            }
            unsigned int excl = run - lsum;
            int need = skneed;
            if (excl < (unsigned int)need && run >= (unsigned int)need) {
                unsigned int cum = excl;
                int b = t * 4;
                if (cum + h0 < (unsigned int)need) { cum += h0; ++b;
                    if (cum + h1 < (unsigned int)need) { cum += h1; ++b;
                        if (cum + h2 < (unsigned int)need) { cum += h2; ++b; } } }
                sprefix = pfx | ((unsigned int)b << rs);
                skneed = need - (int)cum;
            }
        }
        __syncthreads();
    }

    unsigned int Sstar = sprefix;
    int neq = skneed;
#pragma unroll
    for (int j = 0; j < 4; ++j) {
        if (sb[j] < Sstar) {
            unsigned int p = atomicAdd(&scnt, 1u);
            okeys[p] = ((unsigned long long)sb[j] << 32) | ei[j];
        } else if (sb[j] == Sstar) {
            unsigned int p = atomicAdd(&ecnt, 1u);
            ecand[p] = ei[j];
        }
    }
    __syncthreads();
    if (t == 0) {
        unsigned int base = scnt;
        unsigned int ne = ecnt;
        for (int q = 0; q < neq; ++q) {
            unsigned int mn = 0xffffffffu; int mi = 0;
            for (unsigned int e = 0; e < ne; ++e)
                if (ecand[e] < mn) { mn = ecand[e]; mi = (int)e; }
            okeys[base + q] = ((unsigned long long)Sstar << 32) | mn;
            ecand[mi] = 0xffffffffu;
        }
    }
    __syncthreads();
    if (t < CAP_) {
        unsigned long long mine = okeys[t];
        int r = 0;
#pragma unroll 8
        for (int q = 0; q < CAP_; ++q) r += (okeys[q] < mine) ? 1 : 0;
        idx[blockIdx.x * CAP_ + r] = (int)(mine & 0xffffffffu);
    }
}

// ---------------- gather + RMSNorm(g1) -> h (bf16) ----------------
__global__ __launch_bounds__(256) void k_gather_rms(const float* __restrict__ x,
                                                    const int* __restrict__ idx,
                                                    const float* __restrict__ g,
                                                    unsigned short* __restrict__ h) {
    int r = blockIdx.x;
    int b = r >> 9;
    int src = idx[r] & (T_ - 1);
    const float* xr = x + ((size_t)b * T_ + src) * D_;
    int c = threadIdx.x * 4;
    float4 xv = *(const float4*)(xr + c);
    float ss = xv.x*xv.x + xv.y*xv.y + xv.z*xv.z + xv.w*xv.w;
#pragma unroll
    for (int o = 32; o; o >>= 1) ss += __shfl_xor(ss, o);
    __shared__ float red[4];
    int lane = threadIdx.x & 63, w = threadIdx.x >> 6;
    if (lane == 0) red[w] = ss;
    __syncthreads();
    float tot = red[0] + red[1] + red[2] + red[3];
    float scale = rsqrtf(tot * (1.f / D_) + 1e-6f);
    float4 gv = *(const float4*)(g + c);
    ushort4 hv;
    hv.x = f2bf(xv.x * scale * gv.x);
    hv.y = f2bf(xv.y * scale * gv.y);
    hv.z = f2bf(xv.z * scale * gv.z);
    hv.w = f2bf(xv.w * scale * gv.w);
    *(ushort4*)(h + (size_t)r * D_ + c) = hv;
}

// ---------------- MFMA GEMM 64x128 (BK=64), DOUBLE-BUFFERED (r18) ----------------
__global__ __launch_bounds__(256) void k_gemm64g(const unsigned short* __restrict__ A,
                                                 const unsigned short* __restrict__ Bw,
                                                 unsigned short* __restrict__ C,
                                                 int Nout, int Kr) {
    __shared__ __align__(16) unsigned short As[2][64 * 64];    // 16KB
    __shared__ __align__(16) unsigned short Bs[2][128 * 64];   // 32KB
    int m0 = blockIdx.x * 64;
    int n0 = blockIdx.y * 128;
    int t = threadIdx.x;
    int w = t >> 6, lane = t & 63;
    int lr = lane & 15, lg = lane >> 4;
    int l8 = lane >> 3, lm8 = lane & 7;

    int arow = w * 16 + l8;           // + j*8
    int acb0 = lm8 ^ (arow & 7), acb1 = lm8 ^ ((arow + 8) & 7);
    int brow = w * 32 + l8;
    int bcb[4];
#pragma unroll
    for (int j = 0; j < 4; ++j) bcb[j] = lm8 ^ ((brow + j * 8) & 7);

    f32x4 acc[4][2];
#pragma unroll
    for (int mi = 0; mi < 4; ++mi)
#pragma unroll
        for (int ni = 0; ni < 2; ++ni) acc[mi][ni] = {0.f, 0.f, 0.f, 0.f};

#define STAGE_G(buf, k0)                                                          \
    {                                                                             \
        gload_lds16(A + (size_t)(m0 + arow) * Kr + (k0) + acb0 * 8,               \
                    &As[buf][(w * 16) * 64]);                                     \
        gload_lds16(A + (size_t)(m0 + arow + 8) * Kr + (k0) + acb1 * 8,           \
                    &As[buf][(w * 16 + 8) * 64]);                                 \
        _Pragma("unroll")                                                         \
        for (int j = 0; j < 4; ++j)                                               \
            gload_lds16(Bw + (size_t)(n0 + brow + j * 8) * Kr + (k0) + bcb[j] * 8,\
                        &Bs[buf][(w * 32 + j * 8) * 64]);                         \
    }

    int nk = Kr >> 6;
    STAGE_G(0, 0);
    __syncthreads();
    for (int kt = 0; kt < nk; ++kt) {
        int cur = kt & 1;
        if (kt + 1 < nk) STAGE_G(cur ^ 1, (kt + 1) << 6);
#pragma unroll
        for (int kh = 0; kh < 2; ++kh) {
            s16x8 af[4], bf[2];
#pragma unroll
            for (int i = 0; i < 4; ++i) {
                int row = i * 16 + lr;
                int pb = (kh * 4 + lg) ^ (row & 7);
                af[i] = *(const s16x8*)&As[cur][row * 64 + pb * 8];
            }
#pragma unroll
            for (int i = 0; i < 2; ++i) {
                int row = w * 32 + i * 16 + lr;
                int pb = (kh * 4 + lg) ^ (row & 7);
                bf[i] = *(const s16x8*)&Bs[cur][row * 64 + pb * 8];
            }
#pragma unroll
            for (int mi = 0; mi < 4; ++mi)
#pragma unroll
                for (int ni = 0; ni < 2; ++ni)
                    acc[mi][ni] = __builtin_amdgcn_mfma_f32_16x16x32_bf16(af[mi], bf[ni],
                                                                          acc[mi][ni], 0, 0, 0);
        }
        __syncthreads();
    }
#undef STAGE_G
    int orow0 = m0 + (lg << 2);
    int ocol0 = n0 + w * 32 + lr;
#pragma unroll
    for (int ni = 0; ni < 2; ++ni) {
        int col = ocol0 + ni * 16;
        if (col < Nout) {
#pragma unroll
            for (int mi = 0; mi < 4; ++mi)
#pragma unroll
                for (int i = 0; i < 4; ++i)
                    C[(size_t)(orow0 + mi * 16 + i) * Nout + col] = f2bf(acc[mi][ni][i]);
        }
    }
}

// ---------------- FUSED W1/W2 GEMM, DOUBLE-BUFFERED (r18) ----------------
__global__ __launch_bounds__(256) void k_gemm64g2(const unsigned short* __restrict__ A,
                                                  const unsigned short* __restrict__ B1,
                                                  const unsigned short* __restrict__ B2,
                                                  unsigned short* __restrict__ F,
                                                  int Nout, int Kr) {
    __shared__ __align__(16) unsigned short As[2][64 * 64];     // 16KB
    __shared__ __align__(16) unsigned short B1s[2][128 * 64];   // 32KB
    __shared__ __align__(16) unsigned short B2s[2][128 * 64];   // 32KB
    int m0 = blockIdx.x * 64;
    int n0 = blockIdx.y * 128;
    int t = threadIdx.x;
    int w = t >> 6, lane = t & 63;
    int lr = lane & 15, lg = lane >> 4;
    int l8 = lane >> 3, lm8 = lane & 7;

    int arow = w * 16 + l8;
    int acb0 = lm8 ^ (arow & 7), acb1 = lm8 ^ ((arow + 8) & 7);
    int brow = w * 32 + l8;
    int bcb[4];
#pragma unroll
    for (int j = 0; j < 4; ++j) bcb[j] = lm8 ^ ((brow + j * 8) & 7);

    f32x4 accU[4][2], accG[4][2];
#pragma unroll
    for (int mi = 0; mi < 4; ++mi)
#pragma unroll
        for (int ni = 0; ni < 2; ++ni) {
            accU[mi][ni] = {0.f, 0.f, 0.f, 0.f};
            accG[mi][ni] = {0.f, 0.f, 0.f, 0.f};
        }

#define STAGE_G2(buf, k0)                                                          \
    {                                                                              \
        gload_lds16(A + (size_t)(m0 + arow) * Kr + (k0) + acb0 * 8,                \
                    &As[buf][(w * 16) * 64]);                                      \
        gload_lds16(A + (size_t)(m0 + arow + 8) * Kr + (k0) + acb1 * 8,            \
                    &As[buf][(w * 16 + 8) * 64]);                                  \
        _Pragma("unroll")                                                          \
        for (int j = 0; j < 4; ++j) {                                              \
            size_t goff = (size_t)(n0 + brow + j * 8) * Kr + (k0) + bcb[j] * 8;    \
            gload_lds16(B1 + goff, &B1s[buf][(w * 32 + j * 8) * 64]);              \
            gload_lds16(B2 + goff, &B2s[buf][(w * 32 + j * 8) * 64]);              \
        }                                                                          \
    }

    int nk = Kr >> 6;
    STAGE_G2(0, 0);
    __syncthreads();
    for (int kt = 0; kt < nk; ++kt) {
        int cur = kt & 1;
        if (kt + 1 < nk) STAGE_G2(cur ^ 1, (kt + 1) << 6);
#pragma unroll
        for (int kh = 0; kh < 2; ++kh) {
            s16x8 af[4], b1f[2], b2f[2];
#pragma unroll
            for (int i = 0; i < 4; ++i) {
                int row = i * 16 + lr;
                int pb = (kh * 4 + lg) ^ (row & 7);
                af[i] = *(const s16x8*)&As[cur][row * 64 + pb * 8];
            }
#pragma unroll
            for (int i = 0; i < 2; ++i) {
                int row = w * 32 + i * 16 + lr;
                int pb = (kh * 4 + lg) ^ (row & 7);
                b1f[i] = *(const s16x8*)&B1s[cur][row * 64 + pb * 8];
                b2f[i] = *(const s16x8*)&B2s[cur][row * 64 + pb * 8];
            }
#pragma unroll
            for (int mi = 0; mi < 4; ++mi)
#pragma unroll
                for (int ni = 0; ni < 2; ++ni) {
                    accU[mi][ni] = __builtin_amdgcn_mfma_f32_16x16x32_bf16(af[mi], b1f[ni],
                                                                           accU[mi][ni], 0, 0, 0);
                    accG[mi][ni] = __builtin_amdgcn_mfma_f32_16x16x32_bf16(af[mi], b2f[ni],
                                                                           accG[mi][ni], 0, 0, 0);
                }
        }
        __syncthreads();
    }
#undef STAGE_G2
    int orow0 = m0 + (lg << 2);
    int ocol0 = n0 + w * 32 + lr;
#pragma unroll
    for (int ni = 0; ni < 2; ++ni) {
        int col = ocol0 + ni * 16;
        if (col < Nout) {
#pragma unroll
            for (int mi = 0; mi < 4; ++mi)
#pragma unroll
                for (int i = 0; i < 4; ++i) {
                    float u = accU[mi][ni][i];
                    float sl = u / (1.f + __expf(-u));
                    F[(size_t)(orow0 + mi * 16 + i) * Nout + col] = f2bf(sl * accG[mi][ni][i]);
                }
        }
    }
}

// ---------------- MFMA flash attention, KV-tile = 64 (causal, gathered) ----------------
// One workgroup per (qtile=64, head, batch); 4 waves x 16 q-rows.
// Ks[64][72], Vt[64][72] ([d][kv]), Ps[4][16][72]. 27.6KB LDS.
// Per 64-kv tile: 8 QK^T MFMA + 8 PV MFMA, 3 barriers (was 6 for 2x32).
__global__ __launch_bounds__(256) void k_attn_mfma(const unsigned short* __restrict__ qkv,
                                                   unsigned short* __restrict__ o) {
    __shared__ __align__(16) unsigned short Ks[64][72];     // [kv][hd 0..63]
    __shared__ __align__(16) unsigned short Vt[64][72];     // [d][kv 0..63]
    __shared__ __align__(16) unsigned short Ps[4][16][72];  // per-wave P [q][kv 0..63]
    int qt = blockIdx.x, h = blockIdx.y, b = blockIdx.z;
    int q0 = qt * 64;
    int t = threadIdx.x, w = t >> 6, lane = t & 63;
    int lr = lane & 15, lg = lane >> 4;
    const unsigned short* base = qkv + (size_t)b * CAP_ * 3 * D_;

    int qrow = q0 + w * 16 + lr;
    const unsigned short* qp = base + (size_t)qrow * 3 * D_ + h * 64;
    s16x8 aq0 = *(const s16x8*)(qp + lg * 8);
    s16x8 aq1 = *(const s16x8*)(qp + 32 + lg * 8);

    f32x4 zero = {0.f, 0.f, 0.f, 0.f};
    f32x4 oacc[4] = {zero, zero, zero, zero};
    float m_[4], l_[4];
#pragma unroll
    for (int i = 0; i < 4; ++i) { m_[i] = -3.0e38f; l_[i] = 0.f; }

    int qbase = q0 + w * 16 + lg * 4;
    int ntile = qt + 1;                     // 64-kv tiles

    int skv = t >> 2, sc = (t & 3) * 16;    // staging: 64 rows, 4 thr/row, 16 cols
    for (int kt = 0; kt < ntile; ++kt) {
        int kv0 = kt << 6;
        {
            const unsigned short* kr = base + (size_t)(kv0 + skv) * 3 * D_ + D_     + h * 64 + sc;
            const unsigned short* vr = base + (size_t)(kv0 + skv) * 3 * D_ + 2 * D_ + h * 64 + sc;
            *(u16x8*)&Ks[skv][sc]     = *(const u16x8*)kr;
            *(u16x8*)&Ks[skv][sc + 8] = *(const u16x8*)(kr + 8);
            u16x8 v0 = *(const u16x8*)vr;
            u16x8 v1 = *(const u16x8*)(vr + 8);
#pragma unroll
            for (int j = 0; j < 8; ++j) {
                Vt[sc + j][skv]     = v0[j];
                Vt[sc + 8 + j][skv] = v1[j];
            }
        }
        __syncthreads();
        // ---- QK^T: S[16q][64kv] as 4 C-frags ----
        f32x4 s_[4] = {zero, zero, zero, zero};
#pragma unroll
        for (int qi = 0; qi < 4; ++qi) {
            s16x8 k0 = *(const s16x8*)&Ks[qi * 16 + lr][lg * 8];
            s16x8 k1 = *(const s16x8*)&Ks[qi * 16 + lr][32 + lg * 8];
            s_[qi] = __builtin_amdgcn_mfma_f32_16x16x32_bf16(aq0, k0, s_[qi], 0, 0, 0);
            s_[qi] = __builtin_amdgcn_mfma_f32_16x16x32_bf16(aq1, k1, s_[qi], 0, 0, 0);
        }
        // ---- scale + causal mask ----
#pragma unroll
        for (int qi = 0; qi < 4; ++qi)
#pragma unroll
            for (int i = 0; i < 4; ++i) {
                float v = s_[qi][i] * 0.125f;
                if (kv0 + qi * 16 + lr > qbase + i) v = -3.0e38f;
                s_[qi][i] = v;
            }
        // ---- online softmax ----
        float pm[4];
#pragma unroll
        for (int i = 0; i < 4; ++i)
            pm[i] = fmaxf(fmaxf(s_[0][i], s_[1][i]), fmaxf(s_[2][i], s_[3][i]));
#pragma unroll
        for (int d = 1; d < 16; d <<= 1) {
#pragma unroll
            for (int i = 0; i < 4; ++i) pm[i] = fmaxf(pm[i], __shfl_xor(pm[i], d));
        }
        float p[4][4], ps[4], scl[4];
#pragma unroll
        for (int i = 0; i < 4; ++i) {
            float mn = fmaxf(m_[i], pm[i]);
            scl[i] = __expf(m_[i] - mn);
            ps[i] = 0.f;
#pragma unroll
            for (int qi = 0; qi < 4; ++qi) {
                p[qi][i] = __expf(s_[qi][i] - mn);
                ps[i] += p[qi][i];
            }
            m_[i] = mn;
        }
#pragma unroll
        for (int d = 1; d < 16; d <<= 1) {
#pragma unroll
            for (int i = 0; i < 4; ++i) ps[i] += __shfl_xor(ps[i], d);
        }
#pragma unroll
        for (int i = 0; i < 4; ++i) l_[i] = l_[i] * scl[i] + ps[i];
#pragma unroll
        for (int dg = 0; dg < 4; ++dg)
#pragma unroll
            for (int i = 0; i < 4; ++i) oacc[dg][i] *= scl[i];
        // ---- P -> bf16 -> per-wave LDS; barrier; A-frags ----
#pragma unroll
        for (int qi = 0; qi < 4; ++qi)
#pragma unroll
            for (int i = 0; i < 4; ++i)
                Ps[w][lg * 4 + i][qi * 16 + lr] = f2bf(p[qi][i]);
        __syncthreads();
        s16x8 pa0 = *(const s16x8*)&Ps[w][lr][lg * 8];
        s16x8 pa1 = *(const s16x8*)&Ps[w][lr][32 + lg * 8];
        // ---- PV: O[16q][64d] += P[16,64] * V[64,64] ----
#pragma unroll
        for (int dg = 0; dg < 4; ++dg) {
            s16x8 vf0 = *(const s16x8*)&Vt[dg * 16 + lr][lg * 8];
            s16x8 vf1 = *(const s16x8*)&Vt[dg * 16 + lr][32 + lg * 8];
            oacc[dg] = __builtin_amdgcn_mfma_f32_16x16x32_bf16(pa0, vf0, oacc[dg], 0, 0, 0);
            oacc[dg] = __builtin_amdgcn_mfma_f32_16x16x32_bf16(pa1, vf1, oacc[dg], 0, 0, 0);
        }
        __syncthreads();
    }
    unsigned short* orow = o + ((size_t)(b * CAP_ + qbase)) * D_ + h * 64;
#pragma unroll
    for (int i = 0; i < 4; ++i) {
        float inv = 1.f / l_[i];
#pragma unroll
        for (int dg = 0; dg < 4; ++dg)
            orow[(size_t)i * D_ + dg * 16 + lr] = f2bf(oacc[dg][i] * inv);
    }
}

// ---------------- y = x_sel + xattn; h2 = rmsnorm(y, g2) ----------------
__global__ __launch_bounds__(256) void k_add_rms(const float* __restrict__ x,
                                                 const int* __restrict__ idx,
                                                 const unsigned short* __restrict__ xattn,
                                                 const float* __restrict__ g,
                                                 unsigned short* __restrict__ y,
                                                 unsigned short* __restrict__ h) {
    int r = blockIdx.x;
    int b = r >> 9;
    int src = idx[r] & (T_ - 1);
    int c = threadIdx.x * 4;
    const float* xr = x + ((size_t)b * T_ + src) * D_;
    float4 xv = *(const float4*)(xr + c);
    size_t off = (size_t)r * D_ + c;
    ushort4 a4 = *(const ushort4*)(xattn + off);
    float v0 = xv.x + bf2f(a4.x);
    float v1 = xv.y + bf2f(a4.y);
    float v2 = xv.z + bf2f(a4.z);
    float v3 = xv.w + bf2f(a4.w);
    float ss = v0*v0 + v1*v1 + v2*v2 + v3*v3;
#pragma unroll
    for (int o = 32; o; o >>= 1) ss += __shfl_xor(ss, o);
    __shared__ float red[4];
    int lane = threadIdx.x & 63, w = threadIdx.x >> 6;
    if (lane == 0) red[w] = ss;
    __syncthreads();
    float tot = red[0] + red[1] + red[2] + red[3];
    float scale = rsqrtf(tot * (1.f / D_) + 1e-6f);
    ushort4 yv;
    yv.x = f2bf(v0); yv.y = f2bf(v1); yv.z = f2bf(v2); yv.w = f2bf(v3);
    *(ushort4*)(y + off) = yv;
    float4 gv = *(const float4*)(g + c);
    ushort4 hv;
    hv.x = f2bf(v0 * scale * gv.x);
    hv.y = f2bf(v1 * scale * gv.y);
    hv.z = f2bf(v2 * scale * gv.z);
    hv.w = f2bf(v3 * scale * gv.w);
    *(ushort4*)(h + off) = hv;
}

// ---------------- scatter: out[b, idx, :] = y + xff  (fp32 out) ----------------
__global__ __launch_bounds__(256) void k_scatter(const unsigned short* __restrict__ y,
                                                 const unsigned short* __restrict__ xff,
                                                 const int* __restrict__ idx,
                                                 float* __restrict__ out) {
    int r = blockIdx.x;
    int b = r >> 9;
    int dst = idx[r] & (T_ - 1);
    int c = threadIdx.x * 4;
    size_t src = (size_t)r * D_ + c;
    ushort4 a4 = *(const ushort4*)(y + src);
    ushort4 f4 = *(const ushort4*)(xff + src);
    float4 o4;
    o4.x = bf2f(a4.x) + bf2f(f4.x);
    o4.y = bf2f(a4.y) + bf2f(f4.y);
    o4.z = bf2f(a4.z) + bf2f(f4.z);
    o4.w = bf2f(a4.w) + bf2f(f4.w);
    *(float4*)(out + ((size_t)b * T_ + dst) * D_ + c) = o4;
}

extern "C" void kernel_launch(void* const* d_in, const int* in_sizes, int n_in,
                              void* d_out, int out_size, void* d_ws, size_t ws_size,
                              hipStream_t stream) {
    const float* x     = (const float*)d_in[0];
    const float* w_rt  = (const float*)d_in[1];
    const float* W_qkv = (const float*)d_in[2];
    const float* W_out = (const float*)d_in[3];
    const float* g1    = (const float*)d_in[4];
    const float* g2    = (const float*)d_in[5];
    const float* W1    = (const float*)d_in[6];
    const float* W2    = (const float*)d_in[7];
    const float* W3    = (const float*)d_in[8];
    float* out = (float*)d_out;

    // ---- workspace: ~37 MiB (identical to r15-r19) ----
    char* p = (char*)d_ws;
    float* scores = (float*)p;
    int*   idx    = (int*)(p + 65536);
    size_t off = 131072;
    const size_t WPAD = (size_t)DFFR * D_;
    unsigned short* WBIG = (unsigned short*)(p + off); off += 2 * WPAD * 2;
    unsigned short* WB2  = WBIG + WPAD;
    unsigned short* R1   = (unsigned short*)(p + off); off += (size_t)M_*3*D_*2;
    unsigned short* R2   = (unsigned short*)(p + off); off += (size_t)M_*D_*2;
    unsigned short* R3   = (unsigned short*)(p + off); off += (size_t)M_*D_*2;
    unsigned short* R4   = (unsigned short*)(p + off); off += (size_t)M_*D_*2;

    unsigned short* h1    = R2;
    unsigned short* qkvb  = R1;
    unsigned short* attno = R2;   // after h1 dead
    unsigned short* xattn = R3;
    unsigned short* ybuf  = R4;
    unsigned short* h2b   = R2;   // after attno dead
    unsigned short* fbuf  = R1;   // after qkvb dead; [2048][DFFP]
    unsigned short* xffb  = R3;   // after xattn dead

    // 1+2. out = x (pass-through) + router scores, one x read
    k_copy_router<<<(B_*T_) / 4, 256, 0, stream>>>(x, w_rt, out, scores);
    // 3. exact top-k
    k_topk<<<B_, 1024, 0, stream>>>(scores, idx);
    // 4. gather + rmsnorm(g1) -> h1 (bf16)
    k_gather_rms<<<M_, 256, 0, stream>>>(x, idx, g1, h1);
    // 5. qkv = h1 @ W_qkv^T   [2048 x 3072], K=1024
    k_f2b<<<2048, 256, 0, stream>>>((const float4*)W_qkv, (ushort4*)WBIG, (3*D_*D_) / 4);
    k_gemm64g<<<dim3(M_/64, 3*D_/128), 256, 0, stream>>>(h1, WBIG, qkvb, 3*D_, D_);
    // 6. MFMA flash attention (KV-tile 64)
    k_attn_mfma<<<dim3(CAP_/64, H_, B_), 256, 0, stream>>>(qkvb, attno);
    // 7. x_attn = o @ W_out^T  [2048 x 1024], K=1024
    k_f2b<<<1024, 256, 0, stream>>>((const float4*)W_out, (ushort4*)WBIG, (D_*D_) / 4);
    k_gemm64g<<<dim3(M_/64, D_/128), 256, 0, stream>>>(attno, WBIG, xattn, D_, D_);
    // 8. y = x_sel + xattn; h2 = rmsnorm(y, g2)
    k_add_rms<<<M_, 256, 0, stream>>>(x, idx, xattn, g2, ybuf, h2b);
    // 9+10. f = silu(h2@W1^T) * (h2@W2^T)  — FUSED
    k_f2b_rowpad<<<2048, 256, 0, stream>>>(W1, WBIG, D_/8, DFF_, DFFR*(D_/8));
    k_f2b_rowpad<<<2048, 256, 0, stream>>>(W2, WB2,  D_/8, DFF_, DFFR*(D_/8));
    k_gemm64g2<<<dim3(M_/64, DFFR/128), 256, 0, stream>>>(h2b, WBIG, WB2, fbuf,
                                                          DFFP, D_);
    // 11. x_ff = f @ W3^T   [2048 x 1024], K=DFFP
    k_f2b_pad<<<2048, 256, 0, stream>>>(W3, WBIG, DFF_, DFFP, D_);
    k_gemm64g<<<dim3(M_/64, D_/128), 256, 0, stream>>>(fbuf, WBIG, xffb, D_, DFFP);
    // 12. out[b, idx, :] = y + x_ff  (fp32)
    k_scatter<<<M_, 256, 0, stream>>>(ybuf, xffb, idx, out);
}

// Round 21
// 200.358 us; speedup vs baseline: 1.1332x; 1.0356x over previous
//
#include <hip/hip_runtime.h>
#include <hip/hip_bf16.h>

// MoD transformer block: B=4, T=4096, D=1024, H=16, HD=64, CAP=512, DFF=2730
// Inputs fp32, output fp32. Round 21: GEMMs 256 -> 512 threads (8 waves) on
// the same 64x128 tile / BK=64 dbuf / ^(row&7) swizzle. r20 g2: occ 13.8%
// (2 blocks/CU x 4 waves), MFMA+VALU only 40% busy -> latency-bound; 8 waves
// doubles resident waves at constant LDS. Attention/glue unchanged.

#define B_   4
#define T_   4096
#define D_   1024
#define H_   16
#define HD_  64
#define CAP_ 512
#define DFF_ 2730
#define DFFP 2752               // DFF padded to mult of 64 (K-path)
#define DFFR 2816               // DFF padded to mult of 128 (B-row tiles)
#define M_   (B_*CAP_)          // 2048 selected rows total

typedef __attribute__((ext_vector_type(8))) short          s16x8;
typedef __attribute__((ext_vector_type(8))) unsigned short u16x8;
typedef __attribute__((ext_vector_type(4))) float          f32x4;

__device__ __forceinline__ float bf2f(unsigned short u) {
    union { float f; unsigned int i; } v; v.i = ((unsigned int)u) << 16; return v.f;
}
__device__ __forceinline__ unsigned short f2bf(float f) {
    union { float f; unsigned int i; } v; v.f = f;
    unsigned int r = v.i + 0x7fffu + ((v.i >> 16) & 1u);   // RNE
    return (unsigned short)(r >> 16);
}

// async global->LDS, 16B per lane; LDS dest = wave-uniform base + lane*16
__device__ __forceinline__ void gload_lds16(const unsigned short* g, unsigned short* l) {
    __builtin_amdgcn_global_load_lds(
        (const __attribute__((address_space(1))) unsigned int*)g,
        (__attribute__((address_space(3))) unsigned int*)l, 16, 0, 0);
}

// ---------------- fused: out = x (fp32) + router scores ----------------
__global__ __launch_bounds__(256) void k_copy_router(const float* __restrict__ x,
                                                     const float* __restrict__ wr,
                                                     float* __restrict__ out,
                                                     float* __restrict__ sc) {
    int gw   = (blockIdx.x * 256 + threadIdx.x) >> 6;   // 0..B*T-1
    int lane = threadIdx.x & 63;
    const float* row = x + (size_t)gw * D_;
    float* orow = out + (size_t)gw * D_;
    float s = 0.f;
#pragma unroll
    for (int p = 0; p < 4; ++p) {
        int c = p * 256 + lane * 4;
        float4 xv = *(const float4*)(row + c);
        float4 wv = *(const float4*)(wr + c);
        *(float4*)(orow + c) = xv;
        s += xv.x * wv.x + xv.y * wv.y + xv.z * wv.z + xv.w * wv.w;
    }
#pragma unroll
    for (int o = 32; o; o >>= 1) s += __shfl_xor(s, o);
    if (lane == 0) sc[gw] = s;
}

// ---------------- fp32 -> bf16 flat convert ----------------
__global__ __launch_bounds__(256) void k_f2b(const float4* __restrict__ s,
                                             ushort4* __restrict__ d, int n4) {
    int i = blockIdx.x * 256 + threadIdx.x;
    int st = gridDim.x * 256;
    for (; i < n4; i += st) {
        float4 v = s[i];
        ushort4 o;
        o.x = f2bf(v.x); o.y = f2bf(v.y); o.z = f2bf(v.z); o.w = f2bf(v.w);
        d[i] = o;
    }
}

// ---------------- fp32 [rows][K] -> bf16 [rowsP][K], pad ROWS zeroed ----------------
__global__ __launch_bounds__(256) void k_f2b_rowpad(const float* __restrict__ src,
                                                    unsigned short* __restrict__ dst,
                                                    int kc, int rows, int total) {
    int g = blockIdx.x * 256 + threadIdx.x;
    int st = gridDim.x * 256;
    for (; g < total; g += st) {
        int row = g / kc;
        u16x8 v = {0, 0, 0, 0, 0, 0, 0, 0};
        if (row < rows) {
            const float* s = src + ((size_t)g) * 8;
#pragma unroll
            for (int j = 0; j < 2; ++j) {
                float4 f = *(const float4*)(s + 4 * j);
                v[4*j]   = f2bf(f.x); v[4*j+1] = f2bf(f.y);
                v[4*j+2] = f2bf(f.z); v[4*j+3] = f2bf(f.w);
            }
        }
        *(u16x8*)(dst + (size_t)g * 8) = v;
    }
}

// ---------------- fp32 [rows][K] -> bf16 [rows][Kp], pad COLS zeroed ----------------
__global__ __launch_bounds__(256) void k_f2b_pad(const float* __restrict__ src,
                                                 unsigned short* __restrict__ dst,
                                                 int K, int Kp, int rows) {
    int g = blockIdx.x * 256 + threadIdx.x;
    int ng = rows * (Kp >> 3);
    int st = gridDim.x * 256;
    for (; g < ng; g += st) {
        int row = g / (Kp >> 3);
        int c = (g - row * (Kp >> 3)) << 3;
        const float* s = src + (size_t)row * K + c;
        u16x8 v;
        if (c + 8 <= K) {
#pragma unroll
            for (int j = 0; j < 4; ++j) {
                float2 f = *(const float2*)(s + 2 * j);
                v[2*j] = f2bf(f.x); v[2*j+1] = f2bf(f.y);
            }
        } else {
#pragma unroll
            for (int j = 0; j < 8; ++j) v[j] = (c + j < K) ? f2bf(s[j]) : (unsigned short)0;
        }
        *(u16x8*)(dst + (size_t)row * Kp + c) = v;
    }
}

// ---------------- exact top-k via radix select + rank scatter ----------------
__global__ __launch_bounds__(1024) void k_topk(const float* __restrict__ sc,
                                               int* __restrict__ idx) {
    __shared__ unsigned int hist[256];
    __shared__ unsigned long long okeys[CAP_];
    __shared__ unsigned int ecand[T_];
    __shared__ unsigned int sprefix;
    __shared__ int skneed;
    __shared__ unsigned int scnt, ecnt;
    int t = threadIdx.x;
    const float* s = sc + (size_t)blockIdx.x * T_;

    unsigned int sb[4], ei[4];
#pragma unroll
    for (int j = 0; j < 4; ++j) {
        int i = j * 1024 + t;
        union { float f; unsigned int u; } v; v.f = s[i];
        unsigned int k = (v.u & 0x80000000u) ? ~v.u : (v.u | 0x80000000u);
        sb[j] = ~k;
        ei[j] = (unsigned int)i;
    }
    if (t == 0) { sprefix = 0; skneed = CAP_; scnt = 0; ecnt = 0; }

#pragma unroll
    for (int rs = 24; rs >= 0; rs -= 8) {
        if (t < 256) hist[t] = 0;
        __syncthreads();
        unsigned int pfx = sprefix;
#pragma unroll
        for (int j = 0; j < 4; ++j) {
            if (((unsigned long long)(sb[j] ^ pfx) >> (rs + 8)) == 0ULL)
                atomicAdd(&hist[(sb[j] >> rs) & 255u], 1u);
        }
        __syncthreads();
        if (t < 64) {
            unsigned int h0 = hist[t * 4], h1 = hist[t * 4 + 1];
            unsigned int h2 = hist[t * 4 + 2], h3 = hist[t * 4 + 3];
            unsigned int lsum = h0 + h1 + h2 + h3;
            unsigned int run = lsum;
#pragma unroll
            for (int d = 1; d < 64; d <<= 1) {
                unsigned int v = __shfl_up(run, d);
                if (t >= d) run += v;
            }
            unsigned int excl = run - lsum;
            int need = skneed;
            if (excl < (unsigned int)need && run >= (unsigned int)need) {
                unsigned int cum = excl;
                int b = t * 4;
                if (cum + h0 < (unsigned int)need) { cum += h0; ++b;
                    if (cum + h1 < (unsigned int)need) { cum += h1; ++b;
                        if (cum + h2 < (unsigned int)need) { cum += h2; ++b; } } }
                sprefix = pfx | ((unsigned int)b << rs);
                skneed = need - (int)cum;
            }
        }
        __syncthreads();
    }

    unsigned int Sstar = sprefix;
    int neq = skneed;
#pragma unroll
    for (int j = 0; j < 4; ++j) {
        if (sb[j] < Sstar) {
            unsigned int p = atomicAdd(&scnt, 1u);
            okeys[p] = ((unsigned long long)sb[j] << 32) | ei[j];
        } else if (sb[j] == Sstar) {
            unsigned int p = atomicAdd(&ecnt, 1u);
            ecand[p] = ei[j];
        }
    }
    __syncthreads();
    if (t == 0) {
        unsigned int base = scnt;
        unsigned int ne = ecnt;
        for (int q = 0; q < neq; ++q) {
            unsigned int mn = 0xffffffffu; int mi = 0;
            for (unsigned int e = 0; e < ne; ++e)
                if (ecand[e] < mn) { mn = ecand[e]; mi = (int)e; }
            okeys[base + q] = ((unsigned long long)Sstar << 32) | mn;
            ecand[mi] = 0xffffffffu;
        }
    }
    __syncthreads();
    if (t < CAP_) {
        unsigned long long mine = okeys[t];
        int r = 0;
#pragma unroll 8
        for (int q = 0; q < CAP_; ++q) r += (okeys[q] < mine) ? 1 : 0;
        idx[blockIdx.x * CAP_ + r] = (int)(mine & 0xffffffffu);
    }
}

// ---------------- gather + RMSNorm(g1) -> h (bf16) ----------------
__global__ __launch_bounds__(256) void k_gather_rms(const float* __restrict__ x,
                                                    const int* __restrict__ idx,
                                                    const float* __restrict__ g,
                                                    unsigned short* __restrict__ h) {
    int r = blockIdx.x;
    int b = r >> 9;
    int src = idx[r] & (T_ - 1);
    const float* xr = x + ((size_t)b * T_ + src) * D_;
    int c = threadIdx.x * 4;
    float4 xv = *(const float4*)(xr + c);
    float ss = xv.x*xv.x + xv.y*xv.y + xv.z*xv.z + xv.w*xv.w;
#pragma unroll
    for (int o = 32; o; o >>= 1) ss += __shfl_xor(ss, o);
    __shared__ float red[4];
    int lane = threadIdx.x & 63, w = threadIdx.x >> 6;
    if (lane == 0) red[w] = ss;
    __syncthreads();
    float tot = red[0] + red[1] + red[2] + red[3];
    float scale = rsqrtf(tot * (1.f / D_) + 1e-6f);
    float4 gv = *(const float4*)(g + c);
    ushort4 hv;
    hv.x = f2bf(xv.x * scale * gv.x);
    hv.y = f2bf(xv.y * scale * gv.y);
    hv.z = f2bf(xv.z * scale * gv.z);
    hv.w = f2bf(xv.w * scale * gv.w);
    *(ushort4*)(h + (size_t)r * D_ + c) = hv;
}

// ---------------- MFMA GEMM 64x128 (BK=64), dbuf, 8 WAVES (512 thr) ----------------
// Wave w owns 64x16 output (acc[4][1]); staging: A 1 inst/wave, B 2 insts/wave.
__global__ __launch_bounds__(512) void k_gemm64g(const unsigned short* __restrict__ A,
                                                 const unsigned short* __restrict__ Bw,
                                                 unsigned short* __restrict__ C,
                                                 int Nout, int Kr) {
    __shared__ __align__(16) unsigned short As[2][64 * 64];    // 16KB
    __shared__ __align__(16) unsigned short Bs[2][128 * 64];   // 32KB
    int m0 = blockIdx.x * 64;
    int n0 = blockIdx.y * 128;
    int t = threadIdx.x;
    int w = t >> 6, lane = t & 63;             // w in [0,8)
    int lr = lane & 15, lg = lane >> 4;
    int l8 = lane >> 3, lm8 = lane & 7;

    int arow = w * 8 + l8;                     // A rows: 8/wave
    int acb  = lm8 ^ (arow & 7);
    int brow = w * 16 + l8;                    // B rows: 16/wave (2 insts)
    int bcb0 = lm8 ^ (brow & 7), bcb1 = lm8 ^ ((brow + 8) & 7);

    f32x4 acc[4];
#pragma unroll
    for (int mi = 0; mi < 4; ++mi) acc[mi] = {0.f, 0.f, 0.f, 0.f};

#define STAGE_G(buf, k0)                                                          \
    {                                                                             \
        gload_lds16(A + (size_t)(m0 + arow) * Kr + (k0) + acb * 8,                \
                    &As[buf][(w * 8) * 64]);                                      \
        gload_lds16(Bw + (size_t)(n0 + brow) * Kr + (k0) + bcb0 * 8,              \
                    &Bs[buf][(w * 16) * 64]);                                     \
        gload_lds16(Bw + (size_t)(n0 + brow + 8) * Kr + (k0) + bcb1 * 8,          \
                    &Bs[buf][(w * 16 + 8) * 64]);                                 \
    }

    int nk = Kr >> 6;
    STAGE_G(0, 0);
    __syncthreads();
    for (int kt = 0; kt < nk; ++kt) {
        int cur = kt & 1;
        if (kt + 1 < nk) STAGE_G(cur ^ 1, (kt + 1) << 6);
#pragma unroll
        for (int kh = 0; kh < 2; ++kh) {
            s16x8 af[4], bf;
#pragma unroll
            for (int i = 0; i < 4; ++i) {
                int row = i * 16 + lr;
                int pb = (kh * 4 + lg) ^ (row & 7);
                af[i] = *(const s16x8*)&As[cur][row * 64 + pb * 8];
            }
            {
                int row = w * 16 + lr;
                int pb = (kh * 4 + lg) ^ (row & 7);
                bf = *(const s16x8*)&Bs[cur][row * 64 + pb * 8];
            }
#pragma unroll
            for (int mi = 0; mi < 4; ++mi)
                acc[mi] = __builtin_amdgcn_mfma_f32_16x16x32_bf16(af[mi], bf, acc[mi], 0, 0, 0);
        }
        __syncthreads();
    }
#undef STAGE_G
    int orow0 = m0 + (lg << 2);
    int col = n0 + w * 16 + lr;
    if (col < Nout) {
#pragma unroll
        for (int mi = 0; mi < 4; ++mi)
#pragma unroll
            for (int i = 0; i < 4; ++i)
                C[(size_t)(orow0 + mi * 16 + i) * Nout + col] = f2bf(acc[mi][i]);
    }
}

// ---------------- FUSED W1/W2 GEMM, dbuf, 8 WAVES: F = silu(A*B1^T)*(A*B2^T) ----------------
__global__ __launch_bounds__(512) void k_gemm64g2(const unsigned short* __restrict__ A,
                                                  const unsigned short* __restrict__ B1,
                                                  const unsigned short* __restrict__ B2,
                                                  unsigned short* __restrict__ F,
                                                  int Nout, int Kr) {
    __shared__ __align__(16) unsigned short As[2][64 * 64];     // 16KB
    __shared__ __align__(16) unsigned short B1s[2][128 * 64];   // 32KB
    __shared__ __align__(16) unsigned short B2s[2][128 * 64];   // 32KB
    int m0 = blockIdx.x * 64;
    int n0 = blockIdx.y * 128;
    int t = threadIdx.x;
    int w = t >> 6, lane = t & 63;
    int lr = lane & 15, lg = lane >> 4;
    int l8 = lane >> 3, lm8 = lane & 7;

    int arow = w * 8 + l8;
    int acb  = lm8 ^ (arow & 7);
    int brow = w * 16 + l8;
    int bcb0 = lm8 ^ (brow & 7), bcb1 = lm8 ^ ((brow + 8) & 7);

    f32x4 accU[4], accG[4];
#pragma unroll
    for (int mi = 0; mi < 4; ++mi) {
        accU[mi] = {0.f, 0.f, 0.f, 0.f};
        accG[mi] = {0.f, 0.f, 0.f, 0.f};
    }

#define STAGE_G2(buf, k0)                                                          \
    {                                                                              \
        gload_lds16(A + (size_t)(m0 + arow) * Kr + (k0) + acb * 8,                 \
                    &As[buf][(w * 8) * 64]);                                       \
        size_t go0 = (size_t)(n0 + brow) * Kr + (k0) + bcb0 * 8;                   \
        size_t go1 = (size_t)(n0 + brow + 8) * Kr + (k0) + bcb1 * 8;               \
        gload_lds16(B1 + go0, &B1s[buf][(w * 16) * 64]);                           \
        gload_lds16(B1 + go1, &B1s[buf][(w * 16 + 8) * 64]);                       \
        gload_lds16(B2 + go0, &B2s[buf][(w * 16) * 64]);                           \
        gload_lds16(B2 + go1, &B2s[buf][(w * 16 + 8) * 64]);                       \
    }

    int nk = Kr >> 6;
    STAGE_G2(0, 0);
    __syncthreads();
    for (int kt = 0; kt < nk; ++kt) {
        int cur = kt & 1;
        if (kt + 1 < nk) STAGE_G2(cur ^ 1, (kt + 1) << 6);
#pragma unroll
        for (int kh = 0; kh < 2; ++kh) {
            s16x8 af[4], b1f, b2f;
#pragma unroll
            for (int i = 0; i < 4; ++i) {
                int row = i * 16 + lr;
                int pb = (kh * 4 + lg) ^ (row & 7);
                af[i] = *(const s16x8*)&As[cur][row * 64 + pb * 8];
            }
            {
                int row = w * 16 + lr;
                int pb = (kh * 4 + lg) ^ (row & 7);
                b1f = *(const s16x8*)&B1s[cur][row * 64 + pb * 8];
                b2f = *(const s16x8*)&B2s[cur][row * 64 + pb * 8];
            }
#pragma unroll
            for (int mi = 0; mi < 4; ++mi) {
                accU[mi] = __builtin_amdgcn_mfma_f32_16x16x32_bf16(af[mi], b1f, accU[mi], 0, 0, 0);
                accG[mi] = __builtin_amdgcn_mfma_f32_16x16x32_bf16(af[mi], b2f, accG[mi], 0, 0, 0);
            }
        }
        __syncthreads();
    }
#undef STAGE_G2
    int orow0 = m0 + (lg << 2);
    int col = n0 + w * 16 + lr;
    if (col < Nout) {
#pragma unroll
        for (int mi = 0; mi < 4; ++mi)
#pragma unroll
            for (int i = 0; i < 4; ++i) {
                float u = accU[mi][i];
                float sl = u / (1.f + __expf(-u));
                F[(size_t)(orow0 + mi * 16 + i) * Nout + col] = f2bf(sl * accG[mi][i]);
            }
    }
}

// ---------------- MFMA flash attention, KV-tile = 64 (causal, gathered) ----------------
__global__ __launch_bounds__(256) void k_attn_mfma(const unsigned short* __restrict__ qkv,
                                                   unsigned short* __restrict__ o) {
    __shared__ __align__(16) unsigned short Ks[64][72];     // [kv][hd 0..63]
    __shared__ __align__(16) unsigned short Vt[64][72];     // [d][kv 0..63]
    __shared__ __align__(16) unsigned short Ps[4][16][72];  // per-wave P [q][kv 0..63]
    int qt = blockIdx.x, h = blockIdx.y, b = blockIdx.z;
    int q0 = qt * 64;
    int t = threadIdx.x, w = t >> 6, lane = t & 63;
    int lr = lane & 15, lg = lane >> 4;
    const unsigned short* base = qkv + (size_t)b * CAP_ * 3 * D_;

    int qrow = q0 + w * 16 + lr;
    const unsigned short* qp = base + (size_t)qrow * 3 * D_ + h * 64;
    s16x8 aq0 = *(const s16x8*)(qp + lg * 8);
    s16x8 aq1 = *(const s16x8*)(qp + 32 + lg * 8);

    f32x4 zero = {0.f, 0.f, 0.f, 0.f};
    f32x4 oacc[4] = {zero, zero, zero, zero};
    float m_[4], l_[4];
#pragma unroll
    for (int i = 0; i < 4; ++i) { m_[i] = -3.0e38f; l_[i] = 0.f; }

    int qbase = q0 + w * 16 + lg * 4;
    int ntile = qt + 1;

    int skv = t >> 2, sc = (t & 3) * 16;
    for (int kt = 0; kt < ntile; ++kt) {
        int kv0 = kt << 6;
        {
            const unsigned short* kr = base + (size_t)(kv0 + skv) * 3 * D_ + D_     + h * 64 + sc;
            const unsigned short* vr = base + (size_t)(kv0 + skv) * 3 * D_ + 2 * D_ + h * 64 + sc;
            *(u16x8*)&Ks[skv][sc]     = *(const u16x8*)kr;
            *(u16x8*)&Ks[skv][sc + 8] = *(const u16x8*)(kr + 8);
            u16x8 v0 = *(const u16x8*)vr;
            u16x8 v1 = *(const u16x8*)(vr + 8);
#pragma unroll
            for (int j = 0; j < 8; ++j) {
                Vt[sc + j][skv]     = v0[j];
                Vt[sc + 8 + j][skv] = v1[j];
            }
        }
        __syncthreads();
        f32x4 s_[4] = {zero, zero, zero, zero};
#pragma unroll
        for (int qi = 0; qi < 4; ++qi) {
            s16x8 k0 = *(const s16x8*)&Ks[qi * 16 + lr][lg * 8];
            s16x8 k1 = *(const s16x8*)&Ks[qi * 16 + lr][32 + lg * 8];
            s_[qi] = __builtin_amdgcn_mfma_f32_16x16x32_bf16(aq0, k0, s_[qi], 0, 0, 0);
            s_[qi] = __builtin_amdgcn_mfma_f32_16x16x32_bf16(aq1, k1, s_[qi], 0, 0, 0);
        }
#pragma unroll
        for (int qi = 0; qi < 4; ++qi)
#pragma unroll
            for (int i = 0; i < 4; ++i) {
                float v = s_[qi][i] * 0.125f;
                if (kv0 + qi * 16 + lr > qbase + i) v = -3.0e38f;
                s_[qi][i] = v;
            }
        float pm[4];
#pragma unroll
        for (int i = 0; i < 4; ++i)
            pm[i] = fmaxf(fmaxf(s_[0][i], s_[1][i]), fmaxf(s_[2][i], s_[3][i]));
#pragma unroll
        for (int d = 1; d < 16; d <<= 1) {
#pragma unroll
            for (int i = 0; i < 4; ++i) pm[i] = fmaxf(pm[i], __shfl_xor(pm[i], d));
        }
        float p[4][4], ps[4], scl[4];
#pragma unroll
        for (int i = 0; i < 4; ++i) {
            float mn = fmaxf(m_[i], pm[i]);
            scl[i] = __expf(m_[i] - mn);
            ps[i] = 0.f;
#pragma unroll
            for (int qi = 0; qi < 4; ++qi) {
                p[qi][i] = __expf(s_[qi][i] - mn);
                ps[i] += p[qi][i];
            }
            m_[i] = mn;
        }
#pragma unroll
        for (int d = 1; d < 16; d <<= 1) {
#pragma unroll
            for (int i = 0; i < 4; ++i) ps[i] += __shfl_xor(ps[i], d);
        }
#pragma unroll
        for (int i = 0; i < 4; ++i) l_[i] = l_[i] * scl[i] + ps[i];
#pragma unroll
        for (int dg = 0; dg < 4; ++dg)
#pragma unroll
            for (int i = 0; i < 4; ++i) oacc[dg][i] *= scl[i];
#pragma unroll
        for (int qi = 0; qi < 4; ++qi)
#pragma unroll
            for (int i = 0; i < 4; ++i)
                Ps[w][lg * 4 + i][qi * 16 + lr] = f2bf(p[qi][i]);
        __syncthreads();
        s16x8 pa0 = *(const s16x8*)&Ps[w][lr][lg * 8];
        s16x8 pa1 = *(const s16x8*)&Ps[w][lr][32 + lg * 8];
#pragma unroll
        for (int dg = 0; dg < 4; ++dg) {
            s16x8 vf0 = *(const s16x8*)&Vt[dg * 16 + lr][lg * 8];
            s16x8 vf1 = *(const s16x8*)&Vt[dg * 16 + lr][32 + lg * 8];
            oacc[dg] = __builtin_amdgcn_mfma_f32_16x16x32_bf16(pa0, vf0, oacc[dg], 0, 0, 0);
            oacc[dg] = __builtin_amdgcn_mfma_f32_16x16x32_bf16(pa1, vf1, oacc[dg], 0, 0, 0);
        }
        __syncthreads();
    }
    unsigned short* orow = o + ((size_t)(b * CAP_ + qbase)) * D_ + h * 64;
#pragma unroll
    for (int i = 0; i < 4; ++i) {
        float inv = 1.f / l_[i];
#pragma unroll
        for (int dg = 0; dg < 4; ++dg)
            orow[(size_t)i * D_ + dg * 16 + lr] = f2bf(oacc[dg][i] * inv);
    }
}

// ---------------- y = x_sel + xattn; h2 = rmsnorm(y, g2) ----------------
__global__ __launch_bounds__(256) void k_add_rms(const float* __restrict__ x,
                                                 const int* __restrict__ idx,
                                                 const unsigned short* __restrict__ xattn,
                                                 const float* __restrict__ g,
                                                 unsigned short* __restrict__ y,
                                                 unsigned short* __restrict__ h) {
    int r = blockIdx.x;
    int b = r >> 9;
    int src = idx[r] & (T_ - 1);
    int c = threadIdx.x * 4;
    const float* xr = x + ((size_t)b * T_ + src) * D_;
    float4 xv = *(const float4*)(xr + c);
    size_t off = (size_t)r * D_ + c;
    ushort4 a4 = *(const ushort4*)(xattn + off);
    float v0 = xv.x + bf2f(a4.x);
    float v1 = xv.y + bf2f(a4.y);
    float v2 = xv.z + bf2f(a4.z);
    float v3 = xv.w + bf2f(a4.w);
    float ss = v0*v0 + v1*v1 + v2*v2 + v3*v3;
#pragma unroll
    for (int o = 32; o; o >>= 1) ss += __shfl_xor(ss, o);
    __shared__ float red[4];
    int lane = threadIdx.x & 63, w = threadIdx.x >> 6;
    if (lane == 0) red[w] = ss;
    __syncthreads();
    float tot = red[0] + red[1] + red[2] + red[3];
    float scale = rsqrtf(tot * (1.f / D_) + 1e-6f);
    ushort4 yv;
    yv.x = f2bf(v0); yv.y = f2bf(v1); yv.z = f2bf(v2); yv.w = f2bf(v3);
    *(ushort4*)(y + off) = yv;
    float4 gv = *(const float4*)(g + c);
    ushort4 hv;
    hv.x = f2bf(v0 * scale * gv.x);
    hv.y = f2bf(v1 * scale * gv.y);
    hv.z = f2bf(v2 * scale * gv.z);
    hv.w = f2bf(v3 * scale * gv.w);
    *(ushort4*)(h + off) = hv;
}

// ---------------- scatter: out[b, idx, :] = y + xff  (fp32 out) ----------------
__global__ __launch_bounds__(256) void k_scatter(const unsigned short* __restrict__ y,
                                                 const unsigned short* __restrict__ xff,
                                                 const int* __restrict__ idx,
                                                 float* __restrict__ out) {
    int r = blockIdx.x;
    int b = r >> 9;
    int dst = idx[r] & (T_ - 1);
    int c = threadIdx.x * 4;
    size_t src = (size_t)r * D_ + c;
    ushort4 a4 = *(const ushort4*)(y + src);
    ushort4 f4 = *(const ushort4*)(xff + src);
    float4 o4;
    o4.x = bf2f(a4.x) + bf2f(f4.x);
    o4.y = bf2f(a4.y) + bf2f(f4.y);
    o4.z = bf2f(a4.z) + bf2f(f4.z);
    o4.w = bf2f(a4.w) + bf2f(f4.w);
    *(float4*)(out + ((size_t)b * T_ + dst) * D_ + c) = o4;
}

extern "C" void kernel_launch(void* const* d_in, const int* in_sizes, int n_in,
                              void* d_out, int out_size, void* d_ws, size_t ws_size,
                              hipStream_t stream) {
    const float* x     = (const float*)d_in[0];
    const float* w_rt  = (const float*)d_in[1];
    const float* W_qkv = (const float*)d_in[2];
    const float* W_out = (const float*)d_in[3];
    const float* g1    = (const float*)d_in[4];
    const float* g2    = (const float*)d_in[5];
    const float* W1    = (const float*)d_in[6];
    const float* W2    = (const float*)d_in[7];
    const float* W3    = (const float*)d_in[8];
    float* out = (float*)d_out;

    // ---- workspace: ~37 MiB (identical to r15-r20) ----
    char* p = (char*)d_ws;
    float* scores = (float*)p;
    int*   idx    = (int*)(p + 65536);
    size_t off = 131072;
    const size_t WPAD = (size_t)DFFR * D_;
    unsigned short* WBIG = (unsigned short*)(p + off); off += 2 * WPAD * 2;
    unsigned short* WB2  = WBIG + WPAD;
    unsigned short* R1   = (unsigned short*)(p + off); off += (size_t)M_*3*D_*2;
    unsigned short* R2   = (unsigned short*)(p + off); off += (size_t)M_*D_*2;
    unsigned short* R3   = (unsigned short*)(p + off); off += (size_t)M_*D_*2;
    unsigned short* R4   = (unsigned short*)(p + off); off += (size_t)M_*D_*2;

    unsigned short* h1    = R2;
    unsigned short* qkvb  = R1;
    unsigned short* attno = R2;   // after h1 dead
    unsigned short* xattn = R3;
    unsigned short* ybuf  = R4;
    unsigned short* h2b   = R2;   // after attno dead
    unsigned short* fbuf  = R1;   // after qkvb dead; [2048][DFFP]
    unsigned short* xffb  = R3;   // after xattn dead

    // 1+2. out = x (pass-through) + router scores, one x read
    k_copy_router<<<(B_*T_) / 4, 256, 0, stream>>>(x, w_rt, out, scores);
    // 3. exact top-k
    k_topk<<<B_, 1024, 0, stream>>>(scores, idx);
    // 4. gather + rmsnorm(g1) -> h1 (bf16)
    k_gather_rms<<<M_, 256, 0, stream>>>(x, idx, g1, h1);
    // 5. qkv = h1 @ W_qkv^T   [2048 x 3072], K=1024
    k_f2b<<<2048, 256, 0, stream>>>((const float4*)W_qkv, (ushort4*)WBIG, (3*D_*D_) / 4);
    k_gemm64g<<<dim3(M_/64, 3*D_/128), 512, 0, stream>>>(h1, WBIG, qkvb, 3*D_, D_);
    // 6. MFMA flash attention (KV-tile 64)
    k_attn_mfma<<<dim3(CAP_/64, H_, B_), 256, 0, stream>>>(qkvb, attno);
    // 7. x_attn = o @ W_out^T  [2048 x 1024], K=1024
    k_f2b<<<1024, 256, 0, stream>>>((const float4*)W_out, (ushort4*)WBIG, (D_*D_) / 4);
    k_gemm64g<<<dim3(M_/64, D_/128), 512, 0, stream>>>(attno, WBIG, xattn, D_, D_);
    // 8. y = x_sel + xattn; h2 = rmsnorm(y, g2)
    k_add_rms<<<M_, 256, 0, stream>>>(x, idx, xattn, g2, ybuf, h2b);
    // 9+10. f = silu(h2@W1^T) * (h2@W2^T)  — FUSED
    k_f2b_rowpad<<<2048, 256, 0, stream>>>(W1, WBIG, D_/8, DFF_, DFFR*(D_/8));
    k_f2b_rowpad<<<2048, 256, 0, stream>>>(W2, WB2,  D_/8, DFF_, DFFR*(D_/8));
    k_gemm64g2<<<dim3(M_/64, DFFR/128), 512, 0, stream>>>(h2b, WBIG, WB2, fbuf,
                                                          DFFP, D_);
    // 11. x_ff = f @ W3^T   [2048 x 1024], K=DFFP
    k_f2b_pad<<<2048, 256, 0, stream>>>(W3, WBIG, DFF_, DFFP, D_);
    k_gemm64g<<<dim3(M_/64, D_/128), 512, 0, stream>>>(fbuf, WBIG, xffb, D_, DFFP);
    // 12. out[b, idx, :] = y + x_ff  (fp32)
    k_scatter<<<M_, 256, 0, stream>>>(ybuf, xffb, idx, out);
}

// Round 22
// 194.986 us; speedup vs baseline: 1.1644x; 1.0276x over previous
//
#include <hip/hip_runtime.h>
#include <hip/hip_bf16.h>

// MoD transformer block: B=4, T=4096, D=1024, H=16, HD=64, CAP=512, DFF=2730
// Inputs fp32, output fp32. Round 22:
//  (a) qkv GEMM -> 128x128 tile, 8 waves 2x4 (16 MFMA/iter/wave vs 12 ds_read;
//      r21's 64x128 8-wave re-read A 8x redundantly, ratio 10 read : 8 MFMA).
//  (b) scatter fused into W3 GEMM epilogue (kills xffb+scatter round-trip).
//  (c) W1/W2 converts merged into one dispatch.

#define B_   4
#define T_   4096
#define D_   1024
#define H_   16
#define HD_  64
#define CAP_ 512
#define DFF_ 2730
#define DFFP 2752               // DFF padded to mult of 64 (K-path)
#define DFFR 2816               // DFF padded to mult of 128 (B-row tiles)
#define M_   (B_*CAP_)          // 2048 selected rows total

typedef __attribute__((ext_vector_type(8))) short          s16x8;
typedef __attribute__((ext_vector_type(8))) unsigned short u16x8;
typedef __attribute__((ext_vector_type(4))) float          f32x4;

__device__ __forceinline__ float bf2f(unsigned short u) {
    union { float f; unsigned int i; } v; v.i = ((unsigned int)u) << 16; return v.f;
}
__device__ __forceinline__ unsigned short f2bf(float f) {
    union { float f; unsigned int i; } v; v.f = f;
    unsigned int r = v.i + 0x7fffu + ((v.i >> 16) & 1u);   // RNE
    return (unsigned short)(r >> 16);
}

// async global->LDS, 16B per lane; LDS dest = wave-uniform base + lane*16
__device__ __forceinline__ void gload_lds16(const unsigned short* g, unsigned short* l) {
    __builtin_amdgcn_global_load_lds(
        (const __attribute__((address_space(1))) unsigned int*)g,
        (__attribute__((address_space(3))) unsigned int*)l, 16, 0, 0);
}

// ---------------- fused: out = x (fp32) + router scores ----------------
__global__ __launch_bounds__(256) void k_copy_router(const float* __restrict__ x,
                                                     const float* __restrict__ wr,
                                                     float* __restrict__ out,
                                                     float* __restrict__ sc) {
    int gw   = (blockIdx.x * 256 + threadIdx.x) >> 6;   // 0..B*T-1
    int lane = threadIdx.x & 63;
    const float* row = x + (size_t)gw * D_;
    float* orow = out + (size_t)gw * D_;
    float s = 0.f;
#pragma unroll
    for (int p = 0; p < 4; ++p) {
        int c = p * 256 + lane * 4;
        float4 xv = *(const float4*)(row + c);
        float4 wv = *(const float4*)(wr + c);
        *(float4*)(orow + c) = xv;
        s += xv.x * wv.x + xv.y * wv.y + xv.z * wv.z + xv.w * wv.w;
    }
#pragma unroll
    for (int o = 32; o; o >>= 1) s += __shfl_xor(s, o);
    if (lane == 0) sc[gw] = s;
}

// ---------------- fp32 -> bf16 flat convert ----------------
__global__ __launch_bounds__(256) void k_f2b(const float4* __restrict__ s,
                                             ushort4* __restrict__ d, int n4) {
    int i = blockIdx.x * 256 + threadIdx.x;
    int st = gridDim.x * 256;
    for (; i < n4; i += st) {
        float4 v = s[i];
        ushort4 o;
        o.x = f2bf(v.x); o.y = f2bf(v.y); o.z = f2bf(v.z); o.w = f2bf(v.w);
        d[i] = o;
    }
}

// ---------------- W1+W2: fp32 [rows][K] -> bf16 [rowsP][K], pad ROWS zeroed ----------------
__global__ __launch_bounds__(256) void k_f2b_rowpad2(const float* __restrict__ s1,
                                                     const float* __restrict__ s2,
                                                     unsigned short* __restrict__ d1,
                                                     unsigned short* __restrict__ d2,
                                                     int kc, int rows, int total) {
    int g = blockIdx.x * 256 + threadIdx.x;
    int st = gridDim.x * 256;
    for (; g < total; g += st) {
        int row = g / kc;
        u16x8 v1 = {0,0,0,0,0,0,0,0}, v2 = {0,0,0,0,0,0,0,0};
        if (row < rows) {
            const float* p1 = s1 + ((size_t)g) * 8;
            const float* p2 = s2 + ((size_t)g) * 8;
#pragma unroll
            for (int j = 0; j < 2; ++j) {
                float4 f1 = *(const float4*)(p1 + 4 * j);
                float4 f2 = *(const float4*)(p2 + 4 * j);
                v1[4*j] = f2bf(f1.x); v1[4*j+1] = f2bf(f1.y);
                v1[4*j+2] = f2bf(f1.z); v1[4*j+3] = f2bf(f1.w);
                v2[4*j] = f2bf(f2.x); v2[4*j+1] = f2bf(f2.y);
                v2[4*j+2] = f2bf(f2.z); v2[4*j+3] = f2bf(f2.w);
            }
        }
        *(u16x8*)(d1 + (size_t)g * 8) = v1;
        *(u16x8*)(d2 + (size_t)g * 8) = v2;
    }
}

// ---------------- fp32 [rows][K] -> bf16 [rows][Kp], pad COLS zeroed ----------------
__global__ __launch_bounds__(256) void k_f2b_pad(const float* __restrict__ src,
                                                 unsigned short* __restrict__ dst,
                                                 int K, int Kp, int rows) {
    int g = blockIdx.x * 256 + threadIdx.x;
    int ng = rows * (Kp >> 3);
    int st = gridDim.x * 256;
    for (; g < ng; g += st) {
        int row = g / (Kp >> 3);
        int c = (g - row * (Kp >> 3)) << 3;
        const float* s = src + (size_t)row * K + c;
        u16x8 v;
        if (c + 8 <= K) {
#pragma unroll
            for (int j = 0; j < 4; ++j) {
                float2 f = *(const float2*)(s + 2 * j);
                v[2*j] = f2bf(f.x); v[2*j+1] = f2bf(f.y);
            }
        } else {
#pragma unroll
            for (int j = 0; j < 8; ++j) v[j] = (c + j < K) ? f2bf(s[j]) : (unsigned short)0;
        }
        *(u16x8*)(dst + (size_t)row * Kp + c) = v;
    }
}

// ---------------- exact top-k via radix select + rank scatter ----------------
__global__ __launch_bounds__(1024) void k_topk(const float* __restrict__ sc,
                                               int* __restrict__ idx) {
    __shared__ unsigned int hist[256];
    __shared__ unsigned long long okeys[CAP_];
    __shared__ unsigned int ecand[T_];
    __shared__ unsigned int sprefix;
    __shared__ int skneed;
    __shared__ unsigned int scnt, ecnt;
    int t = threadIdx.x;
    const float* s = sc + (size_t)blockIdx.x * T_;

    unsigned int sb[4], ei[4];
#pragma unroll
    for (int j = 0; j < 4; ++j) {
        int i = j * 1024 + t;
        union { float f; unsigned int u; } v; v.f = s[i];
        unsigned int k = (v.u & 0x80000000u) ? ~v.u : (v.u | 0x80000000u);
        sb[j] = ~k;
        ei[j] = (unsigned int)i;
    }
    if (t == 0) { sprefix = 0; skneed = CAP_; scnt = 0; ecnt = 0; }

#pragma unroll
    for (int rs = 24; rs >= 0; rs -= 8) {
        if (t < 256) hist[t] = 0;
        __syncthreads();
        unsigned int pfx = sprefix;
#pragma unroll
        for (int j = 0; j < 4; ++j) {
            if (((unsigned long long)(sb[j] ^ pfx) >> (rs + 8)) == 0ULL)
                atomicAdd(&hist[(sb[j] >> rs) & 255u], 1u);
        }
        __syncthreads();
        if (t < 64) {
            unsigned int h0 = hist[t * 4], h1 = hist[t * 4 + 1];
            unsigned int h2 = hist[t * 4 + 2], h3 = hist[t * 4 + 3];
            unsigned int lsum = h0 + h1 + h2 + h3;
            unsigned int run = lsum;
#pragma unroll
            for (int d = 1; d < 64; d <<= 1) {
                unsigned int v = __shfl_up(run, d);
                if (t >= d) run += v;
            }
            unsigned int excl = run - lsum;
            int need = skneed;
            if (excl < (unsigned int)need && run >= (unsigned int)need) {
                unsigned int cum = excl;
                int b = t * 4;
                if (cum + h0 < (unsigned int)need) { cum += h0; ++b;
                    if (cum + h1 < (unsigned int)need) { cum += h1; ++b;
                        if (cum + h2 < (unsigned int)need) { cum += h2; ++b; } } }
                sprefix = pfx | ((unsigned int)b << rs);
                skneed = need - (int)cum;
            }
        }
        __syncthreads();
    }

    unsigned int Sstar = sprefix;
    int neq = skneed;
#pragma unroll
    for (int j = 0; j < 4; ++j) {
        if (sb[j] < Sstar) {
            unsigned int p = atomicAdd(&scnt, 1u);
            okeys[p] = ((unsigned long long)sb[j] << 32) | ei[j];
        } else if (sb[j] == Sstar) {
            unsigned int p = atomicAdd(&ecnt, 1u);
            ecand[p] = ei[j];
        }
    }
    __syncthreads();
    if (t == 0) {
        unsigned int base = scnt;
        unsigned int ne = ecnt;
        for (int q = 0; q < neq; ++q) {
            unsigned int mn = 0xffffffffu; int mi = 0;
            for (unsigned int e = 0; e < ne; ++e)
                if (ecand[e] < mn) { mn = ecand[e]; mi = (int)e; }
            okeys[base + q] = ((unsigned long long)Sstar << 32) | mn;
            ecand[mi] = 0xffffffffu;
        }
    }
    __syncthreads();
    if (t < CAP_) {
        unsigned long long mine = okeys[t];
        int r = 0;
#pragma unroll 8
        for (int q = 0; q < CAP_; ++q) r += (okeys[q] < mine) ? 1 : 0;
        idx[blockIdx.x * CAP_ + r] = (int)(mine & 0xffffffffu);
    }
}

// ---------------- gather + RMSNorm(g1) -> h (bf16) ----------------
__global__ __launch_bounds__(256) void k_gather_rms(const float* __restrict__ x,
                                                    const int* __restrict__ idx,
                                                    const float* __restrict__ g,
                                                    unsigned short* __restrict__ h) {
    int r = blockIdx.x;
    int b = r >> 9;
    int src = idx[r] & (T_ - 1);
    const float* xr = x + ((size_t)b * T_ + src) * D_;
    int c = threadIdx.x * 4;
    float4 xv = *(const float4*)(xr + c);
    float ss = xv.x*xv.x + xv.y*xv.y + xv.z*xv.z + xv.w*xv.w;
#pragma unroll
    for (int o = 32; o; o >>= 1) ss += __shfl_xor(ss, o);
    __shared__ float red[4];
    int lane = threadIdx.x & 63, w = threadIdx.x >> 6;
    if (lane == 0) red[w] = ss;
    __syncthreads();
    float tot = red[0] + red[1] + red[2] + red[3];
    float scale = rsqrtf(tot * (1.f / D_) + 1e-6f);
    float4 gv = *(const float4*)(g + c);
    ushort4 hv;
    hv.x = f2bf(xv.x * scale * gv.x);
    hv.y = f2bf(xv.y * scale * gv.y);
    hv.z = f2bf(xv.z * scale * gv.z);
    hv.w = f2bf(xv.w * scale * gv.w);
    *(ushort4*)(h + (size_t)r * D_ + c) = hv;
}

// ---------------- MFMA GEMM 128x128 (BK=64), dbuf, 8 waves 2x4 ----------------
// Wave w: wm=(w>>2)*64, wn=(w&3)*32; owns 64x32 (acc[4][2]); 16 MFMA/iter.
// Staging: each wave 16 A-rows + 16 B-rows (2+2 insts). LDS 64KB.
__global__ __launch_bounds__(512) void k_gemm128g(const unsigned short* __restrict__ A,
                                                  const unsigned short* __restrict__ Bw,
                                                  unsigned short* __restrict__ C,
                                                  int Nout, int Kr) {
    __shared__ __align__(16) unsigned short As[2][128 * 64];   // 32KB
    __shared__ __align__(16) unsigned short Bs[2][128 * 64];   // 32KB
    int m0 = blockIdx.x * 128;
    int n0 = blockIdx.y * 128;
    int t = threadIdx.x;
    int w = t >> 6, lane = t & 63;
    int lr = lane & 15, lg = lane >> 4;
    int l8 = lane >> 3, lm8 = lane & 7;
    int wm = (w >> 2) * 64, wn = (w & 3) * 32;

    int srow = w * 16 + l8;
    int cb0 = lm8 ^ (srow & 7), cb1 = lm8 ^ ((srow + 8) & 7);

    f32x4 acc[4][2];
#pragma unroll
    for (int mi = 0; mi < 4; ++mi)
#pragma unroll
        for (int ni = 0; ni < 2; ++ni) acc[mi][ni] = {0.f, 0.f, 0.f, 0.f};

#define STAGE_128(buf, k0)                                                        \
    {                                                                             \
        gload_lds16(A + (size_t)(m0 + srow) * Kr + (k0) + cb0 * 8,                \
                    &As[buf][(w * 16) * 64]);                                     \
        gload_lds16(A + (size_t)(m0 + srow + 8) * Kr + (k0) + cb1 * 8,            \
                    &As[buf][(w * 16 + 8) * 64]);                                 \
        gload_lds16(Bw + (size_t)(n0 + srow) * Kr + (k0) + cb0 * 8,               \
                    &Bs[buf][(w * 16) * 64]);                                     \
        gload_lds16(Bw + (size_t)(n0 + srow + 8) * Kr + (k0) + cb1 * 8,           \
                    &Bs[buf][(w * 16 + 8) * 64]);                                 \
    }

    int nk = Kr >> 6;
    STAGE_128(0, 0);
    __syncthreads();
    for (int kt = 0; kt < nk; ++kt) {
        int cur = kt & 1;
        if (kt + 1 < nk) STAGE_128(cur ^ 1, (kt + 1) << 6);
#pragma unroll
        for (int kh = 0; kh < 2; ++kh) {
            s16x8 af[4], bf[2];
#pragma unroll
            for (int i = 0; i < 4; ++i) {
                int row = wm + i * 16 + lr;
                int pb = (kh * 4 + lg) ^ (row & 7);
                af[i] = *(const s16x8*)&As[cur][row * 64 + pb * 8];
            }
#pragma unroll
            for (int i = 0; i < 2; ++i) {
                int row = wn + i * 16 + lr;
                int pb = (kh * 4 + lg) ^ (row & 7);
                bf[i] = *(const s16x8*)&Bs[cur][row * 64 + pb * 8];
            }
#pragma unroll
            for (int mi = 0; mi < 4; ++mi)
#pragma unroll
                for (int ni = 0; ni < 2; ++ni)
                    acc[mi][ni] = __builtin_amdgcn_mfma_f32_16x16x32_bf16(af[mi], bf[ni],
                                                                          acc[mi][ni], 0, 0, 0);
        }
        __syncthreads();
    }
#undef STAGE_128
    int orow0 = m0 + wm + (lg << 2);
    int ocol0 = n0 + wn + lr;
#pragma unroll
    for (int ni = 0; ni < 2; ++ni) {
        int col = ocol0 + ni * 16;
        if (col < Nout) {
#pragma unroll
            for (int mi = 0; mi < 4; ++mi)
#pragma unroll
                for (int i = 0; i < 4; ++i)
                    C[(size_t)(orow0 + mi * 16 + i) * Nout + col] = f2bf(acc[mi][ni][i]);
        }
    }
}

// ---------------- MFMA GEMM 64x128 (BK=64), dbuf, 8 waves ----------------
// EPI==0: C = acc (bf16). EPI==2: out[b, idx[r], col] = bf2f(Y[r,col]) + acc
// (fused y + x_ff scatter; fp32 out).
template<int EPI>
__global__ __launch_bounds__(512) void k_gemm64g(const unsigned short* __restrict__ A,
                                                 const unsigned short* __restrict__ Bw,
                                                 unsigned short* __restrict__ C,
                                                 int Nout, int Kr,
                                                 const unsigned short* __restrict__ Y,
                                                 const int* __restrict__ idxp,
                                                 float* __restrict__ outp) {
    __shared__ __align__(16) unsigned short As[2][64 * 64];    // 16KB
    __shared__ __align__(16) unsigned short Bs[2][128 * 64];   // 32KB
    int m0 = blockIdx.x * 64;
    int n0 = blockIdx.y * 128;
    int t = threadIdx.x;
    int w = t >> 6, lane = t & 63;
    int lr = lane & 15, lg = lane >> 4;
    int l8 = lane >> 3, lm8 = lane & 7;

    int arow = w * 8 + l8;
    int acb  = lm8 ^ (arow & 7);
    int brow = w * 16 + l8;
    int bcb0 = lm8 ^ (brow & 7), bcb1 = lm8 ^ ((brow + 8) & 7);

    f32x4 acc[4];
#pragma unroll
    for (int mi = 0; mi < 4; ++mi) acc[mi] = {0.f, 0.f, 0.f, 0.f};

#define STAGE_G(buf, k0)                                                          \
    {                                                                             \
        gload_lds16(A + (size_t)(m0 + arow) * Kr + (k0) + acb * 8,                \
                    &As[buf][(w * 8) * 64]);                                      \
        gload_lds16(Bw + (size_t)(n0 + brow) * Kr + (k0) + bcb0 * 8,              \
                    &Bs[buf][(w * 16) * 64]);                                     \
        gload_lds16(Bw + (size_t)(n0 + brow + 8) * Kr + (k0) + bcb1 * 8,          \
                    &Bs[buf][(w * 16 + 8) * 64]);                                 \
    }

    int nk = Kr >> 6;
    STAGE_G(0, 0);
    __syncthreads();
    for (int kt = 0; kt < nk; ++kt) {
        int cur = kt & 1;
        if (kt + 1 < nk) STAGE_G(cur ^ 1, (kt + 1) << 6);
#pragma unroll
        for (int kh = 0; kh < 2; ++kh) {
            s16x8 af[4], bf;
#pragma unroll
            for (int i = 0; i < 4; ++i) {
                int row = i * 16 + lr;
                int pb = (kh * 4 + lg) ^ (row & 7);
                af[i] = *(const s16x8*)&As[cur][row * 64 + pb * 8];
            }
            {
                int row = w * 16 + lr;
                int pb = (kh * 4 + lg) ^ (row & 7);
                bf = *(const s16x8*)&Bs[cur][row * 64 + pb * 8];
            }
#pragma unroll
            for (int mi = 0; mi < 4; ++mi)
                acc[mi] = __builtin_amdgcn_mfma_f32_16x16x32_bf16(af[mi], bf, acc[mi], 0, 0, 0);
        }
        __syncthreads();
    }
#undef STAGE_G
    int orow0 = m0 + (lg << 2);
    int col = n0 + w * 16 + lr;
    if (col < Nout) {
#pragma unroll
        for (int mi = 0; mi < 4; ++mi)
#pragma unroll
            for (int i = 0; i < 4; ++i) {
                int r = orow0 + mi * 16 + i;
                if (EPI == 2) {
                    int b = r >> 9;
                    int dst = idxp[r] & (T_ - 1);
                    float yv = bf2f(Y[(size_t)r * D_ + col]);
                    outp[((size_t)(b * T_ + dst)) * D_ + col] = yv + acc[mi][i];
                } else {
                    C[(size_t)r * Nout + col] = f2bf(acc[mi][i]);
                }
            }
    }
}

// ---------------- FUSED W1/W2 GEMM, dbuf, 8 WAVES: F = silu(A*B1^T)*(A*B2^T) ----------------
__global__ __launch_bounds__(512) void k_gemm64g2(const unsigned short* __restrict__ A,
                                                  const unsigned short* __restrict__ B1,
                                                  const unsigned short* __restrict__ B2,
                                                  unsigned short* __restrict__ F,
                                                  int Nout, int Kr) {
    __shared__ __align__(16) unsigned short As[2][64 * 64];     // 16KB
    __shared__ __align__(16) unsigned short B1s[2][128 * 64];   // 32KB
    __shared__ __align__(16) unsigned short B2s[2][128 * 64];   // 32KB
    int m0 = blockIdx.x * 64;
    int n0 = blockIdx.y * 128;
    int t = threadIdx.x;
    int w = t >> 6, lane = t & 63;
    int lr = lane & 15, lg = lane >> 4;
    int l8 = lane >> 3, lm8 = lane & 7;

    int arow = w * 8 + l8;
    int acb  = lm8 ^ (arow & 7);
    int brow = w * 16 + l8;
    int bcb0 = lm8 ^ (brow & 7), bcb1 = lm8 ^ ((brow + 8) & 7);

    f32x4 accU[4], accG[4];
#pragma unroll
    for (int mi = 0; mi < 4; ++mi) {
        accU[mi] = {0.f, 0.f, 0.f, 0.f};
        accG[mi] = {0.f, 0.f, 0.f, 0.f};
    }

#define STAGE_G2(buf, k0)                                                          \
    {                                                                              \
        gload_lds16(A + (size_t)(m0 + arow) * Kr + (k0) + acb * 8,                 \
                    &As[buf][(w * 8) * 64]);                                       \
        size_t go0 = (size_t)(n0 + brow) * Kr + (k0) + bcb0 * 8;                   \
        size_t go1 = (size_t)(n0 + brow + 8) * Kr + (k0) + bcb1 * 8;               \
        gload_lds16(B1 + go0, &B1s[buf][(w * 16) * 64]);                           \
        gload_lds16(B1 + go1, &B1s[buf][(w * 16 + 8) * 64]);                       \
        gload_lds16(B2 + go0, &B2s[buf][(w * 16) * 64]);                           \
        gload_lds16(B2 + go1, &B2s[buf][(w * 16 + 8) * 64]);                       \
    }

    int nk = Kr >> 6;
    STAGE_G2(0, 0);
    __syncthreads();
    for (int kt = 0; kt < nk; ++kt) {
        int cur = kt & 1;
        if (kt + 1 < nk) STAGE_G2(cur ^ 1, (kt + 1) << 6);
#pragma unroll
        for (int kh = 0; kh < 2; ++kh) {
            s16x8 af[4], b1f, b2f;
#pragma unroll
            for (int i = 0; i < 4; ++i) {
                int row = i * 16 + lr;
                int pb = (kh * 4 + lg) ^ (row & 7);
                af[i] = *(const s16x8*)&As[cur][row * 64 + pb * 8];
            }
            {
                int row = w * 16 + lr;
                int pb = (kh * 4 + lg) ^ (row & 7);
                b1f = *(const s16x8*)&B1s[cur][row * 64 + pb * 8];
                b2f = *(const s16x8*)&B2s[cur][row * 64 + pb * 8];
            }
#pragma unroll
            for (int mi = 0; mi < 4; ++mi) {
                accU[mi] = __builtin_amdgcn_mfma_f32_16x16x32_bf16(af[mi], b1f, accU[mi], 0, 0, 0);
                accG[mi] = __builtin_amdgcn_mfma_f32_16x16x32_bf16(af[mi], b2f, accG[mi], 0, 0, 0);
            }
        }
        __syncthreads();
    }
#undef STAGE_G2
    int orow0 = m0 + (lg << 2);
    int col = n0 + w * 16 + lr;
    if (col < Nout) {
#pragma unroll
        for (int mi = 0; mi < 4; ++mi)
#pragma unroll
            for (int i = 0; i < 4; ++i) {
                float u = accU[mi][i];
                float sl = u / (1.f + __expf(-u));
                F[(size_t)(orow0 + mi * 16 + i) * Nout + col] = f2bf(sl * accG[mi][i]);
            }
    }
}

// ---------------- MFMA flash attention, KV-tile = 64 (causal, gathered) ----------------
__global__ __launch_bounds__(256) void k_attn_mfma(const unsigned short* __restrict__ qkv,
                                                   unsigned short* __restrict__ o) {
    __shared__ __align__(16) unsigned short Ks[64][72];
    __shared__ __align__(16) unsigned short Vt[64][72];
    __shared__ __align__(16) unsigned short Ps[4][16][72];
    int qt = blockIdx.x, h = blockIdx.y, b = blockIdx.z;
    int q0 = qt * 64;
    int t = threadIdx.x, w = t >> 6, lane = t & 63;
    int lr = lane & 15, lg = lane >> 4;
    const unsigned short* base = qkv + (size_t)b * CAP_ * 3 * D_;

    int qrow = q0 + w * 16 + lr;
    const unsigned short* qp = base + (size_t)qrow * 3 * D_ + h * 64;
    s16x8 aq0 = *(const s16x8*)(qp + lg * 8);
    s16x8 aq1 = *(const s16x8*)(qp + 32 + lg * 8);

    f32x4 zero = {0.f, 0.f, 0.f, 0.f};
    f32x4 oacc[4] = {zero, zero, zero, zero};
    float m_[4], l_[4];
#pragma unroll
    for (int i = 0; i < 4; ++i) { m_[i] = -3.0e38f; l_[i] = 0.f; }

    int qbase = q0 + w * 16 + lg * 4;
    int ntile = qt + 1;

    int skv = t >> 2, sc = (t & 3) * 16;
    for (int kt = 0; kt < ntile; ++kt) {
        int kv0 = kt << 6;
        {
            const unsigned short* kr = base + (size_t)(kv0 + skv) * 3 * D_ + D_     + h * 64 + sc;
            const unsigned short* vr = base + (size_t)(kv0 + skv) * 3 * D_ + 2 * D_ + h * 64 + sc;
            *(u16x8*)&Ks[skv][sc]     = *(const u16x8*)kr;
            *(u16x8*)&Ks[skv][sc + 8] = *(const u16x8*)(kr + 8);
            u16x8 v0 = *(const u16x8*)vr;
            u16x8 v1 = *(const u16x8*)(vr + 8);
#pragma unroll
            for (int j = 0; j < 8; ++j) {
                Vt[sc + j][skv]     = v0[j];
                Vt[sc + 8 + j][skv] = v1[j];
            }
        }
        __syncthreads();
        f32x4 s_[4] = {zero, zero, zero, zero};
#pragma unroll
        for (int qi = 0; qi < 4; ++qi) {
            s16x8 k0 = *(const s16x8*)&Ks[qi * 16 + lr][lg * 8];
            s16x8 k1 = *(const s16x8*)&Ks[qi * 16 + lr][32 + lg * 8];
            s_[qi] = __builtin_amdgcn_mfma_f32_16x16x32_bf16(aq0, k0, s_[qi], 0, 0, 0);
            s_[qi] = __builtin_amdgcn_mfma_f32_16x16x32_bf16(aq1, k1, s_[qi], 0, 0, 0);
        }
#pragma unroll
        for (int qi = 0; qi < 4; ++qi)
#pragma unroll
            for (int i = 0; i < 4; ++i) {
                float v = s_[qi][i] * 0.125f;
                if (kv0 + qi * 16 + lr > qbase + i) v = -3.0e38f;
                s_[qi][i] = v;
            }
        float pm[4];
#pragma unroll
        for (int i = 0; i < 4; ++i)
            pm[i] = fmaxf(fmaxf(s_[0][i], s_[1][i]), fmaxf(s_[2][i], s_[3][i]));
#pragma unroll
        for (int d = 1; d < 16; d <<= 1) {
#pragma unroll
            for (int i = 0; i < 4; ++i) pm[i] = fmaxf(pm[i], __shfl_xor(pm[i], d));
        }
        float p[4][4], ps[4], scl[4];
#pragma unroll
        for (int i = 0; i < 4; ++i) {
            float mn = fmaxf(m_[i], pm[i]);
            scl[i] = __expf(m_[i] - mn);
            ps[i] = 0.f;
#pragma unroll
            for (int qi = 0; qi < 4; ++qi) {
                p[qi][i] = __expf(s_[qi][i] - mn);
                ps[i] += p[qi][i];
            }
            m_[i] = mn;
        }
#pragma unroll
        for (int d = 1; d < 16; d <<= 1) {
#pragma unroll
            for (int i = 0; i < 4; ++i) ps[i] += __shfl_xor(ps[i], d);
        }
#pragma unroll
        for (int i = 0; i < 4; ++i) l_[i] = l_[i] * scl[i] + ps[i];
#pragma unroll
        for (int dg = 0; dg < 4; ++dg)
#pragma unroll
            for (int i = 0; i < 4; ++i) oacc[dg][i] *= scl[i];
#pragma unroll
        for (int qi = 0; qi < 4; ++qi)
#pragma unroll
            for (int i = 0; i < 4; ++i)
                Ps[w][lg * 4 + i][qi * 16 + lr] = f2bf(p[qi][i]);
        __syncthreads();
        s16x8 pa0 = *(const s16x8*)&Ps[w][lr][lg * 8];
        s16x8 pa1 = *(const s16x8*)&Ps[w][lr][32 + lg * 8];
#pragma unroll
        for (int dg = 0; dg < 4; ++dg) {
            s16x8 vf0 = *(const s16x8*)&Vt[dg * 16 + lr][lg * 8];
            s16x8 vf1 = *(const s16x8*)&Vt[dg * 16 + lr][32 + lg * 8];
            oacc[dg] = __builtin_amdgcn_mfma_f32_16x16x32_bf16(pa0, vf0, oacc[dg], 0, 0, 0);
            oacc[dg] = __builtin_amdgcn_mfma_f32_16x16x32_bf16(pa1, vf1, oacc[dg], 0, 0, 0);
        }
        __syncthreads();
    }
    unsigned short* orow = o + ((size_t)(b * CAP_ + qbase)) * D_ + h * 64;
#pragma unroll
    for (int i = 0; i < 4; ++i) {
        float inv = 1.f / l_[i];
#pragma unroll
        for (int dg = 0; dg < 4; ++dg)
            orow[(size_t)i * D_ + dg * 16 + lr] = f2bf(oacc[dg][i] * inv);
    }
}

// ---------------- y = x_sel + xattn; h2 = rmsnorm(y, g2) ----------------
__global__ __launch_bounds__(256) void k_add_rms(const float* __restrict__ x,
                                                 const int* __restrict__ idx,
                                                 const unsigned short* __restrict__ xattn,
                                                 const float* __restrict__ g,
                                                 unsigned short* __restrict__ y,
                                                 unsigned short* __restrict__ h) {
    int r = blockIdx.x;
    int b = r >> 9;
    int src = idx[r] & (T_ - 1);
    int c = threadIdx.x * 4;
    const float* xr = x + ((size_t)b * T_ + src) * D_;
    float4 xv = *(const float4*)(xr + c);
    size_t off = (size_t)r * D_ + c;
    ushort4 a4 = *(const ushort4*)(xattn + off);
    float v0 = xv.x + bf2f(a4.x);
    float v1 = xv.y + bf2f(a4.y);
    float v2 = xv.z + bf2f(a4.z);
    float v3 = xv.w + bf2f(a4.w);
    float ss = v0*v0 + v1*v1 + v2*v2 + v3*v3;
#pragma unroll
    for (int o = 32; o; o >>= 1) ss += __shfl_xor(ss, o);
    __shared__ float red[4];
    int lane = threadIdx.x & 63, w = threadIdx.x >> 6;
    if (lane == 0) red[w] = ss;
    __syncthreads();
    float tot = red[0] + red[1] + red[2] + red[3];
    float scale = rsqrtf(tot * (1.f / D_) + 1e-6f);
    ushort4 yv;
    yv.x = f2bf(v0); yv.y = f2bf(v1); yv.z = f2bf(v2); yv.w = f2bf(v3);
    *(ushort4*)(y + off) = yv;
    float4 gv = *(const float4*)(g + c);
    ushort4 hv;
    hv.x = f2bf(v0 * scale * gv.x);
    hv.y = f2bf(v1 * scale * gv.y);
    hv.z = f2bf(v2 * scale * gv.z);
    hv.w = f2bf(v3 * scale * gv.w);
    *(ushort4*)(h + off) = hv;
}

extern "C" void kernel_launch(void* const* d_in, const int* in_sizes, int n_in,
                              void* d_out, int out_size, void* d_ws, size_t ws_size,
                              hipStream_t stream) {
    const float* x     = (const float*)d_in[0];
    const float* w_rt  = (const float*)d_in[1];
    const float* W_qkv = (const float*)d_in[2];
    const float* W_out = (const float*)d_in[3];
    const float* g1    = (const float*)d_in[4];
    const float* g2    = (const float*)d_in[5];
    const float* W1    = (const float*)d_in[6];
    const float* W2    = (const float*)d_in[7];
    const float* W3    = (const float*)d_in[8];
    float* out = (float*)d_out;

    // ---- workspace: ~37 MiB (identical layout to r15-r21) ----
    char* p = (char*)d_ws;
    float* scores = (float*)p;
    int*   idx    = (int*)(p + 65536);
    size_t off = 131072;
    const size_t WPAD = (size_t)DFFR * D_;
    unsigned short* WBIG = (unsigned short*)(p + off); off += 2 * WPAD * 2;
    unsigned short* WB2  = WBIG + WPAD;
    unsigned short* R1   = (unsigned short*)(p + off); off += (size_t)M_*3*D_*2;
    unsigned short* R2   = (unsigned short*)(p + off); off += (size_t)M_*D_*2;
    unsigned short* R3   = (unsigned short*)(p + off); off += (size_t)M_*D_*2;
    unsigned short* R4   = (unsigned short*)(p + off); off += (size_t)M_*D_*2;

    unsigned short* h1    = R2;
    unsigned short* qkvb  = R1;
    unsigned short* attno = R2;   // after h1 dead
    unsigned short* xattn = R3;
    unsigned short* ybuf  = R4;
    unsigned short* h2b   = R2;   // after attno dead
    unsigned short* fbuf  = R1;   // after qkvb dead; [2048][DFFP]

    // 1+2. out = x (pass-through) + router scores, one x read
    k_copy_router<<<(B_*T_) / 4, 256, 0, stream>>>(x, w_rt, out, scores);
    // 3. exact top-k
    k_topk<<<B_, 1024, 0, stream>>>(scores, idx);
    // 4. gather + rmsnorm(g1) -> h1 (bf16)
    k_gather_rms<<<M_, 256, 0, stream>>>(x, idx, g1, h1);
    // 5. qkv = h1 @ W_qkv^T   [2048 x 3072], K=1024  (128x128 tile, 384 blocks)
    k_f2b<<<2048, 256, 0, stream>>>((const float4*)W_qkv, (ushort4*)WBIG, (3*D_*D_) / 4);
    k_gemm128g<<<dim3(M_/128, 3*D_/128), 512, 0, stream>>>(h1, WBIG, qkvb, 3*D_, D_);
    // 6. MFMA flash attention (KV-tile 64)
    k_attn_mfma<<<dim3(CAP_/64, H_, B_), 256, 0, stream>>>(qkvb, attno);
    // 7. x_attn = o @ W_out^T  [2048 x 1024], K=1024
    k_f2b<<<1024, 256, 0, stream>>>((const float4*)W_out, (ushort4*)WBIG, (D_*D_) / 4);
    k_gemm64g<0><<<dim3(M_/64, D_/128), 512, 0, stream>>>(attno, WBIG, xattn, D_, D_,
                                                          nullptr, nullptr, nullptr);
    // 8. y = x_sel + xattn; h2 = rmsnorm(y, g2)
    k_add_rms<<<M_, 256, 0, stream>>>(x, idx, xattn, g2, ybuf, h2b);
    // 9+10. f = silu(h2@W1^T) * (h2@W2^T)  — FUSED (one merged convert)
    k_f2b_rowpad2<<<2048, 256, 0, stream>>>(W1, W2, WBIG, WB2, D_/8, DFF_,
                                            DFFR*(D_/8));
    k_gemm64g2<<<dim3(M_/64, DFFR/128), 512, 0, stream>>>(h2b, WBIG, WB2, fbuf,
                                                          DFFP, D_);
    // 11+12. out[b, idx, :] = y + f @ W3^T  — scatter fused into GEMM epilogue
    k_f2b_pad<<<2048, 256, 0, stream>>>(W3, WBIG, DFF_, DFFP, D_);
    k_gemm64g<2><<<dim3(M_/64, D_/128), 512, 0, stream>>>(fbuf, WBIG, nullptr, D_, DFFP,
                                                          ybuf, idx, out);
}

// Round 23
// 191.425 us; speedup vs baseline: 1.1861x; 1.0186x over previous
//
#include <hip/hip_runtime.h>
#include <hip/hip_bf16.h>

// MoD transformer block: B=4, T=4096, D=1024, H=16, HD=64, CAP=512, DFF=2730
// Inputs fp32, output fp32. Round 23:
//  (a) k_gemm64g (W_out, W3+scatter) -> TRIPLE-buffered counted-vmcnt pipeline:
//      stage tile kt+2 at iter kt, s_waitcnt vmcnt(3) (never 0 mid-loop) + raw
//      s_barrier. 72KB LDS keeps 2 blocks/CU (occupancy unchanged). These two
//      GEMMs are grid-starved (256 blocks) -> barrier drain fully exposed.
//  (b) attention: LPT block order (heavy qt first; old layout could give one
//      CU two qt=7 blocks -> 8x tail imbalance).
//  g2 / qkv unchanged as controls.

#define B_   4
#define T_   4096
#define D_   1024
#define H_   16
#define HD_  64
#define CAP_ 512
#define DFF_ 2730
#define DFFP 2752               // DFF padded to mult of 64 (K-path)
#define DFFR 2816               // DFF padded to mult of 128 (B-row tiles)
#define M_   (B_*CAP_)          // 2048 selected rows total

typedef __attribute__((ext_vector_type(8))) short          s16x8;
typedef __attribute__((ext_vector_type(8))) unsigned short u16x8;
typedef __attribute__((ext_vector_type(4))) float          f32x4;

__device__ __forceinline__ float bf2f(unsigned short u) {
    union { float f; unsigned int i; } v; v.i = ((unsigned int)u) << 16; return v.f;
}
__device__ __forceinline__ unsigned short f2bf(float f) {
    union { float f; unsigned int i; } v; v.f = f;
    unsigned int r = v.i + 0x7fffu + ((v.i >> 16) & 1u);   // RNE
    return (unsigned short)(r >> 16);
}

// async global->LDS, 16B per lane; LDS dest = wave-uniform base + lane*16
__device__ __forceinline__ void gload_lds16(const unsigned short* g, unsigned short* l) {
    __builtin_amdgcn_global_load_lds(
        (const __attribute__((address_space(1))) unsigned int*)g,
        (__attribute__((address_space(3))) unsigned int*)l, 16, 0, 0);
}

// ---------------- fused: out = x (fp32) + router scores ----------------
__global__ __launch_bounds__(256) void k_copy_router(const float* __restrict__ x,
                                                     const float* __restrict__ wr,
                                                     float* __restrict__ out,
                                                     float* __restrict__ sc) {
    int gw   = (blockIdx.x * 256 + threadIdx.x) >> 6;   // 0..B*T-1
    int lane = threadIdx.x & 63;
    const float* row = x + (size_t)gw * D_;
    float* orow = out + (size_t)gw * D_;
    float s = 0.f;
#pragma unroll
    for (int p = 0; p < 4; ++p) {
        int c = p * 256 + lane * 4;
        float4 xv = *(const float4*)(row + c);
        float4 wv = *(const float4*)(wr + c);
        *(float4*)(orow + c) = xv;
        s += xv.x * wv.x + xv.y * wv.y + xv.z * wv.z + xv.w * wv.w;
    }
#pragma unroll
    for (int o = 32; o; o >>= 1) s += __shfl_xor(s, o);
    if (lane == 0) sc[gw] = s;
}

// ---------------- fp32 -> bf16 flat convert ----------------
__global__ __launch_bounds__(256) void k_f2b(const float4* __restrict__ s,
                                             ushort4* __restrict__ d, int n4) {
    int i = blockIdx.x * 256 + threadIdx.x;
    int st = gridDim.x * 256;
    for (; i < n4; i += st) {
        float4 v = s[i];
        ushort4 o;
        o.x = f2bf(v.x); o.y = f2bf(v.y); o.z = f2bf(v.z); o.w = f2bf(v.w);
        d[i] = o;
    }
}

// ---------------- W1+W2: fp32 [rows][K] -> bf16 [rowsP][K], pad ROWS zeroed ----------------
__global__ __launch_bounds__(256) void k_f2b_rowpad2(const float* __restrict__ s1,
                                                     const float* __restrict__ s2,
                                                     unsigned short* __restrict__ d1,
                                                     unsigned short* __restrict__ d2,
                                                     int kc, int rows, int total) {
    int g = blockIdx.x * 256 + threadIdx.x;
    int st = gridDim.x * 256;
    for (; g < total; g += st) {
        int row = g / kc;
        u16x8 v1 = {0,0,0,0,0,0,0,0}, v2 = {0,0,0,0,0,0,0,0};
        if (row < rows) {
            const float* p1 = s1 + ((size_t)g) * 8;
            const float* p2 = s2 + ((size_t)g) * 8;
#pragma unroll
            for (int j = 0; j < 2; ++j) {
                float4 f1 = *(const float4*)(p1 + 4 * j);
                float4 f2 = *(const float4*)(p2 + 4 * j);
                v1[4*j] = f2bf(f1.x); v1[4*j+1] = f2bf(f1.y);
                v1[4*j+2] = f2bf(f1.z); v1[4*j+3] = f2bf(f1.w);
                v2[4*j] = f2bf(f2.x); v2[4*j+1] = f2bf(f2.y);
                v2[4*j+2] = f2bf(f2.z); v2[4*j+3] = f2bf(f2.w);
            }
        }
        *(u16x8*)(d1 + (size_t)g * 8) = v1;
        *(u16x8*)(d2 + (size_t)g * 8) = v2;
    }
}

// ---------------- fp32 [rows][K] -> bf16 [rows][Kp], pad COLS zeroed ----------------
__global__ __launch_bounds__(256) void k_f2b_pad(const float* __restrict__ src,
                                                 unsigned short* __restrict__ dst,
                                                 int K, int Kp, int rows) {
    int g = blockIdx.x * 256 + threadIdx.x;
    int ng = rows * (Kp >> 3);
    int st = gridDim.x * 256;
    for (; g < ng; g += st) {
        int row = g / (Kp >> 3);
        int c = (g - row * (Kp >> 3)) << 3;
        const float* s = src + (size_t)row * K + c;
        u16x8 v;
        if (c + 8 <= K) {
#pragma unroll
            for (int j = 0; j < 4; ++j) {
                float2 f = *(const float2*)(s + 2 * j);
                v[2*j] = f2bf(f.x); v[2*j+1] = f2bf(f.y);
            }
        } else {
#pragma unroll
            for (int j = 0; j < 8; ++j) v[j] = (c + j < K) ? f2bf(s[j]) : (unsigned short)0;
        }
        *(u16x8*)(dst + (size_t)row * Kp + c) = v;
    }
}

// ---------------- exact top-k via radix select + rank scatter ----------------
__global__ __launch_bounds__(1024) void k_topk(const float* __restrict__ sc,
                                               int* __restrict__ idx) {
    __shared__ unsigned int hist[256];
    __shared__ unsigned long long okeys[CAP_];
    __shared__ unsigned int ecand[T_];
    __shared__ unsigned int sprefix;
    __shared__ int skneed;
    __shared__ unsigned int scnt, ecnt;
    int t = threadIdx.x;
    const float* s = sc + (size_t)blockIdx.x * T_;

    unsigned int sb[4], ei[4];
#pragma unroll
    for (int j = 0; j < 4; ++j) {
        int i = j * 1024 + t;
        union { float f; unsigned int u; } v; v.f = s[i];
        unsigned int k = (v.u & 0x80000000u) ? ~v.u : (v.u | 0x80000000u);
        sb[j] = ~k;
        ei[j] = (unsigned int)i;
    }
    if (t == 0) { sprefix = 0; skneed = CAP_; scnt = 0; ecnt = 0; }

#pragma unroll
    for (int rs = 24; rs >= 0; rs -= 8) {
        if (t < 256) hist[t] = 0;
        __syncthreads();
        unsigned int pfx = sprefix;
#pragma unroll
        for (int j = 0; j < 4; ++j) {
            if (((unsigned long long)(sb[j] ^ pfx) >> (rs + 8)) == 0ULL)
                atomicAdd(&hist[(sb[j] >> rs) & 255u], 1u);
        }
        __syncthreads();
        if (t < 64) {
            unsigned int h0 = hist[t * 4], h1 = hist[t * 4 + 1];
            unsigned int h2 = hist[t * 4 + 2], h3 = hist[t * 4 + 3];
            unsigned int lsum = h0 + h1 + h2 + h3;
            unsigned int run = lsum;
#pragma unroll
            for (int d = 1; d < 64; d <<= 1) {
                unsigned int v = __shfl_up(run, d);
                if (t >= d) run += v;
            }
            unsigned int excl = run - lsum;
            int need = skneed;
            if (excl < (unsigned int)need && run >= (unsigned int)need) {
                unsigned int cum = excl;
                int b = t * 4;
                if (cum + h0 < (unsigned int)need) { cum += h0; ++b;
                    if (cum + h1 < (unsigned int)need) { cum += h1; ++b;
                        if (cum + h2 < (unsigned int)need) { cum += h2; ++b; } } }
                sprefix = pfx | ((unsigned int)b << rs);
                skneed = need - (int)cum;
            }
        }
        __syncthreads();
    }

    unsigned int Sstar = sprefix;
    int neq = skneed;
#pragma unroll
    for (int j = 0; j < 4; ++j) {
        if (sb[j] < Sstar) {
            unsigned int p = atomicAdd(&scnt, 1u);
            okeys[p] = ((unsigned long long)sb[j] << 32) | ei[j];
        } else if (sb[j] == Sstar) {
            unsigned int p = atomicAdd(&ecnt, 1u);
            ecand[p] = ei[j];
        }
    }
    __syncthreads();
    if (t == 0) {
        unsigned int base = scnt;
        unsigned int ne = ecnt;
        for (int q = 0; q < neq; ++q) {
            unsigned int mn = 0xffffffffu; int mi = 0;
            for (unsigned int e = 0; e < ne; ++e)
                if (ecand[e] < mn) { mn = ecand[e]; mi = (int)e; }
            okeys[base + q] = ((unsigned long long)Sstar << 32) | mn;
            ecand[mi] = 0xffffffffu;
        }
    }
    __syncthreads();
    if (t < CAP_) {
        unsigned long long mine = okeys[t];
        int r = 0;
#pragma unroll 8
        for (int q = 0; q < CAP_; ++q) r += (okeys[q] < mine) ? 1 : 0;
        idx[blockIdx.x * CAP_ + r] = (int)(mine & 0xffffffffu);
    }
}

// ---------------- gather + RMSNorm(g1) -> h (bf16) ----------------
__global__ __launch_bounds__(256) void k_gather_rms(const float* __restrict__ x,
                                                    const int* __restrict__ idx,
                                                    const float* __restrict__ g,
                                                    unsigned short* __restrict__ h) {
    int r = blockIdx.x;
    int b = r >> 9;
    int src = idx[r] & (T_ - 1);
    const float* xr = x + ((size_t)b * T_ + src) * D_;
    int c = threadIdx.x * 4;
    float4 xv = *(const float4*)(xr + c);
    float ss = xv.x*xv.x + xv.y*xv.y + xv.z*xv.z + xv.w*xv.w;
#pragma unroll
    for (int o = 32; o; o >>= 1) ss += __shfl_xor(ss, o);
    __shared__ float red[4];
    int lane = threadIdx.x & 63, w = threadIdx.x >> 6;
    if (lane == 0) red[w] = ss;
    __syncthreads();
    float tot = red[0] + red[1] + red[2] + red[3];
    float scale = rsqrtf(tot * (1.f / D_) + 1e-6f);
    float4 gv = *(const float4*)(g + c);
    ushort4 hv;
    hv.x = f2bf(xv.x * scale * gv.x);
    hv.y = f2bf(xv.y * scale * gv.y);
    hv.z = f2bf(xv.z * scale * gv.z);
    hv.w = f2bf(xv.w * scale * gv.w);
    *(ushort4*)(h + (size_t)r * D_ + c) = hv;
}

// ---------------- MFMA GEMM 128x128 (BK=64), dbuf, 8 waves 2x4 (r22) ----------------
__global__ __launch_bounds__(512) void k_gemm128g(const unsigned short* __restrict__ A,
                                                  const unsigned short* __restrict__ Bw,
                                                  unsigned short* __restrict__ C,
                                                  int Nout, int Kr) {
    __shared__ __align__(16) unsigned short As[2][128 * 64];   // 32KB
    __shared__ __align__(16) unsigned short Bs[2][128 * 64];   // 32KB
    int m0 = blockIdx.x * 128;
    int n0 = blockIdx.y * 128;
    int t = threadIdx.x;
    int w = t >> 6, lane = t & 63;
    int lr = lane & 15, lg = lane >> 4;
    int l8 = lane >> 3, lm8 = lane & 7;
    int wm = (w >> 2) * 64, wn = (w & 3) * 32;

    int srow = w * 16 + l8;
    int cb0 = lm8 ^ (srow & 7), cb1 = lm8 ^ ((srow + 8) & 7);

    f32x4 acc[4][2];
#pragma unroll
    for (int mi = 0; mi < 4; ++mi)
#pragma unroll
        for (int ni = 0; ni < 2; ++ni) acc[mi][ni] = {0.f, 0.f, 0.f, 0.f};

#define STAGE_128(buf, k0)                                                        \
    {                                                                             \
        gload_lds16(A + (size_t)(m0 + srow) * Kr + (k0) + cb0 * 8,                \
                    &As[buf][(w * 16) * 64]);                                     \
        gload_lds16(A + (size_t)(m0 + srow + 8) * Kr + (k0) + cb1 * 8,            \
                    &As[buf][(w * 16 + 8) * 64]);                                 \
        gload_lds16(Bw + (size_t)(n0 + srow) * Kr + (k0) + cb0 * 8,               \
                    &Bs[buf][(w * 16) * 64]);                                     \
        gload_lds16(Bw + (size_t)(n0 + srow + 8) * Kr + (k0) + cb1 * 8,           \
                    &Bs[buf][(w * 16 + 8) * 64]);                                 \
    }

    int nk = Kr >> 6;
    STAGE_128(0, 0);
    __syncthreads();
    for (int kt = 0; kt < nk; ++kt) {
        int cur = kt & 1;
        if (kt + 1 < nk) STAGE_128(cur ^ 1, (kt + 1) << 6);
#pragma unroll
        for (int kh = 0; kh < 2; ++kh) {
            s16x8 af[4], bf[2];
#pragma unroll
            for (int i = 0; i < 4; ++i) {
                int row = wm + i * 16 + lr;
                int pb = (kh * 4 + lg) ^ (row & 7);
                af[i] = *(const s16x8*)&As[cur][row * 64 + pb * 8];
            }
#pragma unroll
            for (int i = 0; i < 2; ++i) {
                int row = wn + i * 16 + lr;
                int pb = (kh * 4 + lg) ^ (row & 7);
                bf[i] = *(const s16x8*)&Bs[cur][row * 64 + pb * 8];
            }
#pragma unroll
            for (int mi = 0; mi < 4; ++mi)
#pragma unroll
                for (int ni = 0; ni < 2; ++ni)
                    acc[mi][ni] = __builtin_amdgcn_mfma_f32_16x16x32_bf16(af[mi], bf[ni],
                                                                          acc[mi][ni], 0, 0, 0);
        }
        __syncthreads();
    }
#undef STAGE_128
    int orow0 = m0 + wm + (lg << 2);
    int ocol0 = n0 + wn + lr;
#pragma unroll
    for (int ni = 0; ni < 2; ++ni) {
        int col = ocol0 + ni * 16;
        if (col < Nout) {
#pragma unroll
            for (int mi = 0; mi < 4; ++mi)
#pragma unroll
                for (int i = 0; i < 4; ++i)
                    C[(size_t)(orow0 + mi * 16 + i) * Nout + col] = f2bf(acc[mi][ni][i]);
        }
    }
}

// ---------------- MFMA GEMM 64x128 (BK=64), TRIPLE-buf counted-vmcnt, 8 waves ----------------
// Per wave per tile: 3 gloads. Stage tile kt+2 at iter kt; s_waitcnt vmcnt(3)
// (never 0 mid-loop) + raw s_barrier. Buffer staged at kt was last read at
// kt-1, whose reads complete before its trailing barrier (MFMA lgkmcnt).
// EPI==0: C = acc. EPI==2: out[b, idx[r], col] = bf2f(Y[r,col]) + acc.
template<int EPI>
__global__ __launch_bounds__(512) void k_gemm64g(const unsigned short* __restrict__ A,
                                                 const unsigned short* __restrict__ Bw,
                                                 unsigned short* __restrict__ C,
                                                 int Nout, int Kr,
                                                 const unsigned short* __restrict__ Y,
                                                 const int* __restrict__ idxp,
                                                 float* __restrict__ outp) {
    __shared__ __align__(16) unsigned short As[3][64 * 64];    // 24KB
    __shared__ __align__(16) unsigned short Bs[3][128 * 64];   // 48KB
    int m0 = blockIdx.x * 64;
    int n0 = blockIdx.y * 128;
    int t = threadIdx.x;
    int w = t >> 6, lane = t & 63;
    int lr = lane & 15, lg = lane >> 4;
    int l8 = lane >> 3, lm8 = lane & 7;

    int arow = w * 8 + l8;
    int acb  = lm8 ^ (arow & 7);
    int brow = w * 16 + l8;
    int bcb0 = lm8 ^ (brow & 7), bcb1 = lm8 ^ ((brow + 8) & 7);

    f32x4 acc[4];
#pragma unroll
    for (int mi = 0; mi < 4; ++mi) acc[mi] = {0.f, 0.f, 0.f, 0.f};

#define STAGE_G(buf, k0)                                                          \
    {                                                                             \
        gload_lds16(A + (size_t)(m0 + arow) * Kr + (k0) + acb * 8,                \
                    &As[buf][(w * 8) * 64]);                                      \
        gload_lds16(Bw + (size_t)(n0 + brow) * Kr + (k0) + bcb0 * 8,              \
                    &Bs[buf][(w * 16) * 64]);                                     \
        gload_lds16(Bw + (size_t)(n0 + brow + 8) * Kr + (k0) + bcb1 * 8,          \
                    &Bs[buf][(w * 16 + 8) * 64]);                                 \
    }

    int nk = Kr >> 6;                 // >= 16 for all our shapes
    STAGE_G(0, 0);
    STAGE_G(1, 64);
    asm volatile("s_waitcnt vmcnt(3)" ::: "memory");
    __builtin_amdgcn_s_barrier();
    for (int kt = 0; kt < nk; ++kt) {
        int cur = kt % 3;
        bool more = (kt + 2 < nk);
        if (more) STAGE_G((kt + 2) % 3, (kt + 2) << 6);
#pragma unroll
        for (int kh = 0; kh < 2; ++kh) {
            s16x8 af[4], bf;
#pragma unroll
            for (int i = 0; i < 4; ++i) {
                int row = i * 16 + lr;
                int pb = (kh * 4 + lg) ^ (row & 7);
                af[i] = *(const s16x8*)&As[cur][row * 64 + pb * 8];
            }
            {
                int row = w * 16 + lr;
                int pb = (kh * 4 + lg) ^ (row & 7);
                bf = *(const s16x8*)&Bs[cur][row * 64 + pb * 8];
            }
#pragma unroll
            for (int mi = 0; mi < 4; ++mi)
                acc[mi] = __builtin_amdgcn_mfma_f32_16x16x32_bf16(af[mi], bf, acc[mi], 0, 0, 0);
        }
        if (kt + 1 < nk) {
            if (more) asm volatile("s_waitcnt vmcnt(3)" ::: "memory");
            else      asm volatile("s_waitcnt vmcnt(0)" ::: "memory");
            __builtin_amdgcn_s_barrier();
        }
    }
#undef STAGE_G
    int orow0 = m0 + (lg << 2);
    int col = n0 + w * 16 + lr;
    if (col < Nout) {
#pragma unroll
        for (int mi = 0; mi < 4; ++mi)
#pragma unroll
            for (int i = 0; i < 4; ++i) {
                int r = orow0 + mi * 16 + i;
                if (EPI == 2) {
                    int b = r >> 9;
                    int dst = idxp[r] & (T_ - 1);
                    float yv = bf2f(Y[(size_t)r * D_ + col]);
                    outp[((size_t)(b * T_ + dst)) * D_ + col] = yv + acc[mi][i];
                } else {
                    C[(size_t)r * Nout + col] = f2bf(acc[mi][i]);
                }
            }
    }
}

// ---------------- FUSED W1/W2 GEMM, dbuf, 8 WAVES (r22): F = silu(A*B1^T)*(A*B2^T) ----------------
__global__ __launch_bounds__(512) void k_gemm64g2(const unsigned short* __restrict__ A,
                                                  const unsigned short* __restrict__ B1,
                                                  const unsigned short* __restrict__ B2,
                                                  unsigned short* __restrict__ F,
                                                  int Nout, int Kr) {
    __shared__ __align__(16) unsigned short As[2][64 * 64];     // 16KB
    __shared__ __align__(16) unsigned short B1s[2][128 * 64];   // 32KB
    __shared__ __align__(16) unsigned short B2s[2][128 * 64];   // 32KB
    int m0 = blockIdx.x * 64;
    int n0 = blockIdx.y * 128;
    int t = threadIdx.x;
    int w = t >> 6, lane = t & 63;
    int lr = lane & 15, lg = lane >> 4;
    int l8 = lane >> 3, lm8 = lane & 7;

    int arow = w * 8 + l8;
    int acb  = lm8 ^ (arow & 7);
    int brow = w * 16 + l8;
    int bcb0 = lm8 ^ (brow & 7), bcb1 = lm8 ^ ((brow + 8) & 7);

    f32x4 accU[4], accG[4];
#pragma unroll
    for (int mi = 0; mi < 4; ++mi) {
        accU[mi] = {0.f, 0.f, 0.f, 0.f};
        accG[mi] = {0.f, 0.f, 0.f, 0.f};
    }

#define STAGE_G2(buf, k0)                                                          \
    {                                                                              \
        gload_lds16(A + (size_t)(m0 + arow) * Kr + (k0) + acb * 8,                 \
                    &As[buf][(w * 8) * 64]);                                       \
        size_t go0 = (size_t)(n0 + brow) * Kr + (k0) + bcb0 * 8;                   \
        size_t go1 = (size_t)(n0 + brow + 8) * Kr + (k0) + bcb1 * 8;               \
        gload_lds16(B1 + go0, &B1s[buf][(w * 16) * 64]);                           \
        gload_lds16(B1 + go1, &B1s[buf][(w * 16 + 8) * 64]);                       \
        gload_lds16(B2 + go0, &B2s[buf][(w * 16) * 64]);                           \
        gload_lds16(B2 + go1, &B2s[buf][(w * 16 + 8) * 64]);                       \
    }

    int nk = Kr >> 6;
    STAGE_G2(0, 0);
    __syncthreads();
    for (int kt = 0; kt < nk; ++kt) {
        int cur = kt & 1;
        if (kt + 1 < nk) STAGE_G2(cur ^ 1, (kt + 1) << 6);
#pragma unroll
        for (int kh = 0; kh < 2; ++kh) {
            s16x8 af[4], b1f, b2f;
#pragma unroll
            for (int i = 0; i < 4; ++i) {
                int row = i * 16 + lr;
                int pb = (kh * 4 + lg) ^ (row & 7);
                af[i] = *(const s16x8*)&As[cur][row * 64 + pb * 8];
            }
            {
                int row = w * 16 + lr;
                int pb = (kh * 4 + lg) ^ (row & 7);
                b1f = *(const s16x8*)&B1s[cur][row * 64 + pb * 8];
                b2f = *(const s16x8*)&B2s[cur][row * 64 + pb * 8];
            }
#pragma unroll
            for (int mi = 0; mi < 4; ++mi) {
                accU[mi] = __builtin_amdgcn_mfma_f32_16x16x32_bf16(af[mi], b1f, accU[mi], 0, 0, 0);
                accG[mi] = __builtin_amdgcn_mfma_f32_16x16x32_bf16(af[mi], b2f, accG[mi], 0, 0, 0);
            }
        }
        __syncthreads();
    }
#undef STAGE_G2
    int orow0 = m0 + (lg << 2);
    int col = n0 + w * 16 + lr;
    if (col < Nout) {
#pragma unroll
        for (int mi = 0; mi < 4; ++mi)
#pragma unroll
            for (int i = 0; i < 4; ++i) {
                float u = accU[mi][i];
                float sl = u / (1.f + __expf(-u));
                F[(size_t)(orow0 + mi * 16 + i) * Nout + col] = f2bf(sl * accG[mi][i]);
            }
    }
}

// ---------------- MFMA flash attention, KV-tile = 64, LPT block order ----------------
// 1D grid 512: qt = 7 - (i>>6) (heavy first), h = i&15, b = (i>>4)&3.
__global__ __launch_bounds__(256) void k_attn_mfma(const unsigned short* __restrict__ qkv,
                                                   unsigned short* __restrict__ o) {
    __shared__ __align__(16) unsigned short Ks[64][72];
    __shared__ __align__(16) unsigned short Vt[64][72];
    __shared__ __align__(16) unsigned short Ps[4][16][72];
    int i_ = blockIdx.x;
    int qt = 7 - (i_ >> 6), h = i_ & 15, b = (i_ >> 4) & 3;
    int q0 = qt * 64;
    int t = threadIdx.x, w = t >> 6, lane = t & 63;
    int lr = lane & 15, lg = lane >> 4;
    const unsigned short* base = qkv + (size_t)b * CAP_ * 3 * D_;

    int qrow = q0 + w * 16 + lr;
    const unsigned short* qp = base + (size_t)qrow * 3 * D_ + h * 64;
    s16x8 aq0 = *(const s16x8*)(qp + lg * 8);
    s16x8 aq1 = *(const s16x8*)(qp + 32 + lg * 8);

    f32x4 zero = {0.f, 0.f, 0.f, 0.f};
    f32x4 oacc[4] = {zero, zero, zero, zero};
    float m_[4], l_[4];
#pragma unroll
    for (int i = 0; i < 4; ++i) { m_[i] = -3.0e38f; l_[i] = 0.f; }

    int qbase = q0 + w * 16 + lg * 4;
    int ntile = qt + 1;

    int skv = t >> 2, sc = (t & 3) * 16;
    for (int kt = 0; kt < ntile; ++kt) {
        int kv0 = kt << 6;
        {
            const unsigned short* kr = base + (size_t)(kv0 + skv) * 3 * D_ + D_     + h * 64 + sc;
            const unsigned short* vr = base + (size_t)(kv0 + skv) * 3 * D_ + 2 * D_ + h * 64 + sc;
            *(u16x8*)&Ks[skv][sc]     = *(const u16x8*)kr;
            *(u16x8*)&Ks[skv][sc + 8] = *(const u16x8*)(kr + 8);
            u16x8 v0 = *(const u16x8*)vr;
            u16x8 v1 = *(const u16x8*)(vr + 8);
#pragma unroll
            for (int j = 0; j < 8; ++j) {
                Vt[sc + j][skv]     = v0[j];
                Vt[sc + 8 + j][skv] = v1[j];
            }
        }
        __syncthreads();
        f32x4 s_[4] = {zero, zero, zero, zero};
#pragma unroll
        for (int qi = 0; qi < 4; ++qi) {
            s16x8 k0 = *(const s16x8*)&Ks[qi * 16 + lr][lg * 8];
            s16x8 k1 = *(const s16x8*)&Ks[qi * 16 + lr][32 + lg * 8];
            s_[qi] = __builtin_amdgcn_mfma_f32_16x16x32_bf16(aq0, k0, s_[qi], 0, 0, 0);
            s_[qi] = __builtin_amdgcn_mfma_f32_16x16x32_bf16(aq1, k1, s_[qi], 0, 0, 0);
        }
#pragma unroll
        for (int qi = 0; qi < 4; ++qi)
#pragma unroll
            for (int i = 0; i < 4; ++i) {
                float v = s_[qi][i] * 0.125f;
                if (kv0 + qi * 16 + lr > qbase + i) v = -3.0e38f;
                s_[qi][i] = v;
            }
        float pm[4];
#pragma unroll
        for (int i = 0; i < 4; ++i)
            pm[i] = fmaxf(fmaxf(s_[0][i], s_[1][i]), fmaxf(s_[2][i], s_[3][i]));
#pragma unroll
        for (int d = 1; d < 16; d <<= 1) {
#pragma unroll
            for (int i = 0; i < 4; ++i) pm[i] = fmaxf(pm[i], __shfl_xor(pm[i], d));
        }
        float p[4][4], ps[4], scl[4];
#pragma unroll
        for (int i = 0; i < 4; ++i) {
            float mn = fmaxf(m_[i], pm[i]);
            scl[i] = __expf(m_[i] - mn);
            ps[i] = 0.f;
#pragma unroll
            for (int qi = 0; qi < 4; ++qi) {
                p[qi][i] = __expf(s_[qi][i] - mn);
                ps[i] += p[qi][i];
            }
            m_[i] = mn;
        }
#pragma unroll
        for (int d = 1; d < 16; d <<= 1) {
#pragma unroll
            for (int i = 0; i < 4; ++i) ps[i] += __shfl_xor(ps[i], d);
        }
#pragma unroll
        for (int i = 0; i < 4; ++i) l_[i] = l_[i] * scl[i] + ps[i];
#pragma unroll
        for (int dg = 0; dg < 4; ++dg)
#pragma unroll
            for (int i = 0; i < 4; ++i) oacc[dg][i] *= scl[i];
#pragma unroll
        for (int qi = 0; qi < 4; ++qi)
#pragma unroll
            for (int i = 0; i < 4; ++i)
                Ps[w][lg * 4 + i][qi * 16 + lr] = f2bf(p[qi][i]);
        __syncthreads();
        s16x8 pa0 = *(const s16x8*)&Ps[w][lr][lg * 8];
        s16x8 pa1 = *(const s16x8*)&Ps[w][lr][32 + lg * 8];
#pragma unroll
        for (int dg = 0; dg < 4; ++dg) {
            s16x8 vf0 = *(const s16x8*)&Vt[dg * 16 + lr][lg * 8];
            s16x8 vf1 = *(const s16x8*)&Vt[dg * 16 + lr][32 + lg * 8];
            oacc[dg] = __builtin_amdgcn_mfma_f32_16x16x32_bf16(pa0, vf0, oacc[dg], 0, 0, 0);
            oacc[dg] = __builtin_amdgcn_mfma_f32_16x16x32_bf16(pa1, vf1, oacc[dg], 0, 0, 0);
        }
        __syncthreads();
    }
    unsigned short* orow = o + ((size_t)(b * CAP_ + qbase)) * D_ + h * 64;
#pragma unroll
    for (int i = 0; i < 4; ++i) {
        float inv = 1.f / l_[i];
#pragma unroll
        for (int dg = 0; dg < 4; ++dg)
            orow[(size_t)i * D_ + dg * 16 + lr] = f2bf(oacc[dg][i] * inv);
    }
}

// ---------------- y = x_sel + xattn; h2 = rmsnorm(y, g2) ----------------
__global__ __launch_bounds__(256) void k_add_rms(const float* __restrict__ x,
                                                 const int* __restrict__ idx,
                                                 const unsigned short* __restrict__ xattn,
                                                 const float* __restrict__ g,
                                                 unsigned short* __restrict__ y,
                                                 unsigned short* __restrict__ h) {
    int r = blockIdx.x;
    int b = r >> 9;
    int src = idx[r] & (T_ - 1);
    int c = threadIdx.x * 4;
    const float* xr = x + ((size_t)b * T_ + src) * D_;
    float4 xv = *(const float4*)(xr + c);
    size_t off = (size_t)r * D_ + c;
    ushort4 a4 = *(const ushort4*)(xattn + off);
    float v0 = xv.x + bf2f(a4.x);
    float v1 = xv.y + bf2f(a4.y);
    float v2 = xv.z + bf2f(a4.z);
    float v3 = xv.w + bf2f(a4.w);
    float ss = v0*v0 + v1*v1 + v2*v2 + v3*v3;
#pragma unroll
    for (int o = 32; o; o >>= 1) ss += __shfl_xor(ss, o);
    __shared__ float red[4];
    int lane = threadIdx.x & 63, w = threadIdx.x >> 6;
    if (lane == 0) red[w] = ss;
    __syncthreads();
    float tot = red[0] + red[1] + red[2] + red[3];
    float scale = rsqrtf(tot * (1.f / D_) + 1e-6f);
    ushort4 yv;
    yv.x = f2bf(v0); yv.y = f2bf(v1); yv.z = f2bf(v2); yv.w = f2bf(v3);
    *(ushort4*)(y + off) = yv;
    float4 gv = *(const float4*)(g + c);
    ushort4 hv;
    hv.x = f2bf(v0 * scale * gv.x);
    hv.y = f2bf(v1 * scale * gv.y);
    hv.z = f2bf(v2 * scale * gv.z);
    hv.w = f2bf(v3 * scale * gv.w);
    *(ushort4*)(h + off) = hv;
}

extern "C" void kernel_launch(void* const* d_in, const int* in_sizes, int n_in,
                              void* d_out, int out_size, void* d_ws, size_t ws_size,
                              hipStream_t stream) {
    const float* x     = (const float*)d_in[0];
    const float* w_rt  = (const float*)d_in[1];
    const float* W_qkv = (const float*)d_in[2];
    const float* W_out = (const float*)d_in[3];
    const float* g1    = (const float*)d_in[4];
    const float* g2    = (const float*)d_in[5];
    const float* W1    = (const float*)d_in[6];
    const float* W2    = (const float*)d_in[7];
    const float* W3    = (const float*)d_in[8];
    float* out = (float*)d_out;

    // ---- workspace: ~37 MiB (identical layout to r15-r22) ----
    char* p = (char*)d_ws;
    float* scores = (float*)p;
    int*   idx    = (int*)(p + 65536);
    size_t off = 131072;
    const size_t WPAD = (size_t)DFFR * D_;
    unsigned short* WBIG = (unsigned short*)(p + off); off += 2 * WPAD * 2;
    unsigned short* WB2  = WBIG + WPAD;
    unsigned short* R1   = (unsigned short*)(p + off); off += (size_t)M_*3*D_*2;
    unsigned short* R2   = (unsigned short*)(p + off); off += (size_t)M_*D_*2;
    unsigned short* R3   = (unsigned short*)(p + off); off += (size_t)M_*D_*2;
    unsigned short* R4   = (unsigned short*)(p + off); off += (size_t)M_*D_*2;

    unsigned short* h1    = R2;
    unsigned short* qkvb  = R1;
    unsigned short* attno = R2;   // after h1 dead
    unsigned short* xattn = R3;
    unsigned short* ybuf  = R4;
    unsigned short* h2b   = R2;   // after attno dead
    unsigned short* fbuf  = R1;   // after qkvb dead; [2048][DFFP]

    // 1+2. out = x (pass-through) + router scores, one x read
    k_copy_router<<<(B_*T_) / 4, 256, 0, stream>>>(x, w_rt, out, scores);
    // 3. exact top-k
    k_topk<<<B_, 1024, 0, stream>>>(scores, idx);
    // 4. gather + rmsnorm(g1) -> h1 (bf16)
    k_gather_rms<<<M_, 256, 0, stream>>>(x, idx, g1, h1);
    // 5. qkv = h1 @ W_qkv^T   [2048 x 3072], K=1024  (128x128 tile)
    k_f2b<<<2048, 256, 0, stream>>>((const float4*)W_qkv, (ushort4*)WBIG, (3*D_*D_) / 4);
    k_gemm128g<<<dim3(M_/128, 3*D_/128), 512, 0, stream>>>(h1, WBIG, qkvb, 3*D_, D_);
    // 6. MFMA flash attention (KV-tile 64, LPT order)
    k_attn_mfma<<<dim3((CAP_/64) * H_ * B_), 256, 0, stream>>>(qkvb, attno);
    // 7. x_attn = o @ W_out^T  [2048 x 1024], K=1024  (3-buf counted vmcnt)
    k_f2b<<<1024, 256, 0, stream>>>((const float4*)W_out, (ushort4*)WBIG, (D_*D_) / 4);
    k_gemm64g<0><<<dim3(M_/64, D_/128), 512, 0, stream>>>(attno, WBIG, xattn, D_, D_,
                                                          nullptr, nullptr, nullptr);
    // 8. y = x_sel + xattn; h2 = rmsnorm(y, g2)
    k_add_rms<<<M_, 256, 0, stream>>>(x, idx, xattn, g2, ybuf, h2b);
    // 9+10. f = silu(h2@W1^T) * (h2@W2^T)  — FUSED (one merged convert)
    k_f2b_rowpad2<<<2048, 256, 0, stream>>>(W1, W2, WBIG, WB2, D_/8, DFF_,
                                            DFFR*(D_/8));
    k_gemm64g2<<<dim3(M_/64, DFFR/128), 512, 0, stream>>>(h2b, WBIG, WB2, fbuf,
                                                          DFFP, D_);
    // 11+12. out[b, idx, :] = y + f @ W3^T  — scatter fused, 3-buf counted vmcnt
    k_f2b_pad<<<2048, 256, 0, stream>>>(W3, WBIG, DFF_, DFFP, D_);
    k_gemm64g<2><<<dim3(M_/64, D_/128), 512, 0, stream>>>(fbuf, WBIG, nullptr, D_, DFFP,
                                                          ybuf, idx, out);
}